// Round 8
// baseline (381.942 us; speedup 1.0000x reference)
//
#include <hip/hip_runtime.h>
#include <math.h>

// MultiheadAttentionQ: W8A8 fake-quant MHA. S=2048, B=2, D=1024, H=16, hd=64.
// R18: R17 + tile-staged ("pre-swizzled") GLOBAL layout for all i8 GEMM
// operands (A1/A2/Wi8/Hint8/Wo8). off(m,k) = (m>>4)<<14 | (k>>6)<<10 |
// ((k>>4)&3)<<8 | (m&15)<<4 | (k&15): each wave's gl2lds stage is ONE
// contiguous 1KB stream (perfect coalescing), and the LDS fragment read is
// chunk*1024 + lane*16 — the R12 pattern that measured SQ_LDS_BANK_CONFLICT=0
// (R17 measured 9.4M with the row-major chunk reads; LDS pipe was the
// critical path: ~4.5k cyc/step/CU vs 640 MFMA). Producers (digitize,
// quantw, quant8) write identical values at permuted addresses; fragments,
// MFMA order, epilogue unchanged -> bit-identical result. gemm_i8out also
// moved to the R17 8-wave/512-thread shape. Attention unchanged.

typedef _Float16 f16;
typedef _Float16 half8 __attribute__((ext_vector_type(8)));
typedef _Float16 half4 __attribute__((ext_vector_type(4)));
typedef _Float16 half2v __attribute__((ext_vector_type(2)));
typedef __fp16 fp16x2 __attribute__((ext_vector_type(2)));
typedef float floatx4 __attribute__((ext_vector_type(4)));
typedef int int4v __attribute__((ext_vector_type(4)));

#define QMAX 127.0f

#define SLOT_WI 0
#define SLOT_WO 1
#define SLOT_XQ 2
#define SLOT_XK 3
#define SLOT_XV 4
#define SLOT_HD 5
#define SLOT_Y  6
#define SLOT_Q  7
#define SLOT_A  8   // shared absmax of query/key/value (15-bit digitization scale)

__device__ __forceinline__ float slot_scale(const unsigned* slots, int slot, float premul) {
  if (slot < 0) return 1.0f;
  return fmaxf(__uint_as_float(slots[slot]) * premul / QMAX, 1e-8f);
}

__device__ __forceinline__ float slot_scaleA(const unsigned* slots) {
  return fmaxf(__uint_as_float(slots[SLOT_A]) / 16256.0f, 1e-8f);
}

__device__ __forceinline__ void gl2lds16(const void* gsrc, void* ldst) {
  __builtin_amdgcn_global_load_lds((__attribute__((address_space(1))) void*)gsrc,
                                   (__attribute__((address_space(3))) void*)ldst, 16, 0, 0);
}

__device__ __forceinline__ half2v pack2(float a, float b) {
  fp16x2 r = __builtin_amdgcn_cvt_pkrtz(a, b);
  return __builtin_bit_cast(half2v, r);
}

// Tile-staged layout for i8 GEMM operands (K=1024 fixed):
// 16-row stripe x 64-col chunk = 1KB; within: byte (seg*256 + row*16 + b),
// seg=(k>>4)&3, row=m&15, b=k&15. Wave stages chunk with src=base+lane*16.
__device__ __forceinline__ size_t swz(int m, int k) {
  return ((size_t)(m >> 4) << 14) + (size_t)(((k >> 6) << 10) +
         (((k >> 4) & 3) << 8) + ((m & 15) << 4) + (k & 15));
}

__global__ __launch_bounds__(64) void init_slots_k(unsigned* slots) {
  if (threadIdx.x < 16) slots[threadIdx.x] = 0u;
}

// Fused absmax: Wi (blocks < 768), Wo (768..1024), q/k/v -> SLOT_A (1024..2560).
__global__ __launch_bounds__(256) void absmax3_k(const float* __restrict__ Wi,
                                                 const float* __restrict__ Wo,
                                                 const float* __restrict__ q,
                                                 const float* __restrict__ k,
                                                 const float* __restrict__ v,
                                                 unsigned* __restrict__ slots) {
  __shared__ float red[256];
  int tid = threadIdx.x;
  int bid = blockIdx.x;
  const float4* x4;
  int n4, i0, stride, slot;
  if (bid < 768) {
    x4 = (const float4*)Wi; n4 = 786432; i0 = bid * 256 + tid;
    stride = 768 * 256; slot = SLOT_WI;
  } else if (bid < 1024) {
    x4 = (const float4*)Wo; n4 = 262144; i0 = (bid - 768) * 256 + tid;
    stride = 256 * 256; slot = SLOT_WO;
  } else {
    int r = bid - 1024;
    int t = r >> 9;
    x4 = (const float4*)(t == 0 ? q : (t == 1 ? k : v));
    n4 = 1048576; i0 = (r & 511) * 256 + tid;
    stride = 512 * 256; slot = SLOT_A;
  }
  float lmax = 0.f;
  for (int i = i0; i < n4; i += stride) {
    float4 vv = x4[i];
    lmax = fmaxf(lmax, fmaxf(fmaxf(fabsf(vv.x), fabsf(vv.y)), fmaxf(fabsf(vv.z), fabsf(vv.w))));
  }
  red[tid] = lmax; __syncthreads();
  for (int sh = 128; sh > 0; sh >>= 1) {
    if (tid < sh) red[tid] = fmaxf(red[tid], red[tid + sh]);
    __syncthreads();
  }
  if (tid == 0) atomicMax(&slots[slot], __float_as_uint(red[0]));
}

// Fused weight quant: Wi -> i8 codes (blocks < 768), Wo -> i8 codes.
// Both written in tile-staged layout (consumed only by the i8 GEMMs).
__global__ __launch_bounds__(256) void quantw_k(const float* __restrict__ Wi,
                                                const float* __restrict__ Wo,
                                                char* __restrict__ Wi8,
                                                char* __restrict__ Wo8,
                                                const unsigned* __restrict__ slots) {
  int tid = threadIdx.x;
  if (blockIdx.x < 768) {
    float s = slot_scale(slots, SLOT_WI, 1.0f);
    const float4* in4 = (const float4*)Wi;
    for (int i = blockIdx.x * 256 + tid; i < 786432; i += 768 * 256) {
      float4 v = in4[i];
      int n = i >> 8, kk = (i & 255) * 4;
      char4 o;
      o.x = (signed char)(int)fminf(fmaxf(rintf(v.x / s), -128.0f), 127.0f);
      o.y = (signed char)(int)fminf(fmaxf(rintf(v.y / s), -128.0f), 127.0f);
      o.z = (signed char)(int)fminf(fmaxf(rintf(v.z / s), -128.0f), 127.0f);
      o.w = (signed char)(int)fminf(fmaxf(rintf(v.w / s), -128.0f), 127.0f);
      *(char4*)(Wi8 + swz(n, kk)) = o;
    }
  } else {
    float s = slot_scale(slots, SLOT_WO, 1.0f);
    const float4* in4 = (const float4*)Wo;
    for (int i = (blockIdx.x - 768) * 256 + tid; i < 262144; i += 256 * 256) {
      float4 v = in4[i];
      int n = i >> 8, kk = (i & 255) * 4;
      char4 o;
      o.x = (signed char)(int)fminf(fmaxf(rintf(v.x / s), -128.0f), 127.0f);
      o.y = (signed char)(int)fminf(fmaxf(rintf(v.y / s), -128.0f), 127.0f);
      o.z = (signed char)(int)fminf(fmaxf(rintf(v.z / s), -128.0f), 127.0f);
      o.w = (signed char)(int)fminf(fmaxf(rintf(v.w / s), -128.0f), 127.0f);
      *(char4*)(Wo8 + swz(n, kk)) = o;
    }
  }
}

// q/k/v fp32 -> 2-digit i8 fixed point, written in tile-staged layout.
__global__ __launch_bounds__(256) void digitize_k(const float* __restrict__ q,
                                                  const float* __restrict__ k,
                                                  const float* __restrict__ v,
                                                  char* __restrict__ A1,
                                                  char* __restrict__ A2,
                                                  const unsigned* __restrict__ slots) {
  float inv = 1.0f / slot_scaleA(slots);
  for (int i = blockIdx.x * 256 + threadIdx.x; i < 3145728; i += gridDim.x * 256) {
    int t = i >> 20;
    int g = i & 1048575;
    const float4* src = (const float4*)(t == 0 ? q : (t == 1 ? k : v));
    float4 x = src[g];
    int m = g >> 8, kk = (g & 255) * 4;
    float xs[4] = {x.x, x.y, x.z, x.w};
    signed char c1s[4], c2s[4];
#pragma unroll
    for (int u = 0; u < 4; ++u) {
      float qv = fminf(fmaxf(rintf(xs[u] * inv), -16256.0f), 16256.0f);
      float c1 = rintf(qv * 0.0078125f);
      c1s[u] = (signed char)(int)c1;
      c2s[u] = (signed char)(int)(qv - 128.0f * c1);
    }
    size_t off = (size_t)t * 4194304 + swz(m, kk);
    *(char4*)(A1 + off) = make_char4(c1s[0], c1s[1], c1s[2], c1s[3]);
    *(char4*)(A2 + off) = make_char4(c2s[0], c2s[1], c2s[2], c2s[3]);
  }
}

// fp32 -> fp32 fake-quant (n*s).
__global__ __launch_bounds__(256) void quantf_k(const float* __restrict__ in, float* __restrict__ out,
                                                int n4, unsigned* __restrict__ slots,
                                                int sSlot, float premul) {
  float s = slot_scale(slots, sSlot, premul);
  const float4* in4 = (const float4*)in;
  float4* out4 = (float4*)out;
  for (int i = blockIdx.x * 256 + threadIdx.x; i < n4; i += gridDim.x * 256) {
    float4 v = in4[i];
    float xs[4] = {v.x, v.y, v.z, v.w};
#pragma unroll
    for (int u = 0; u < 4; ++u) {
      float r = rintf((xs[u] * premul) / s);
      r = fminf(fmaxf(r, -128.0f), 127.0f);
      xs[u] = r * s;
    }
    out4[i] = make_float4(xs[0], xs[1], xs[2], xs[3]);
  }
}

// fp32 -> f16 integer codes. Optionally records absmax of quantized value.
__global__ __launch_bounds__(256) void quanti_k(const float* __restrict__ in, f16* __restrict__ out,
                                                int n4, unsigned* __restrict__ slots,
                                                int sSlot, int outAbsSlot) {
  __shared__ float red[256];
  float s = slot_scale(slots, sSlot, 1.0f);
  float lmax = 0.f;
  const float4* in4 = (const float4*)in;
  for (int i = blockIdx.x * 256 + threadIdx.x; i < n4; i += gridDim.x * 256) {
    float4 v = in4[i];
    float xs[4] = {v.x, v.y, v.z, v.w};
    half4 o;
#pragma unroll
    for (int u = 0; u < 4; ++u) {
      float r = rintf(xs[u] / s);
      r = fminf(fmaxf(r, -128.0f), 127.0f);
      o[u] = (f16)r;
      lmax = fmaxf(lmax, fabsf(r));
    }
    *(half4*)(out + (size_t)i * 4) = o;
  }
  if (outAbsSlot >= 0) {
    int tid = threadIdx.x;
    red[tid] = lmax; __syncthreads();
    for (int sh = 128; sh > 0; sh >>= 1) {
      if (tid < sh) red[tid] = fmaxf(red[tid], red[tid + sh]);
      __syncthreads();
    }
    if (tid == 0) atomicMax(&slots[outAbsSlot], __float_as_uint(red[0] * s));
  }
}

// fp32 -> i8 codes (Hd -> Hint8), written in tile-staged layout (row len 1024).
__global__ __launch_bounds__(256) void quant8_k(const float* __restrict__ in, char* __restrict__ out,
                                                int n4, const unsigned* __restrict__ slots,
                                                int sSlot) {
  float s = slot_scale(slots, sSlot, 1.0f);
  const float4* in4 = (const float4*)in;
  for (int i = blockIdx.x * 256 + threadIdx.x; i < n4; i += gridDim.x * 256) {
    float4 v = in4[i];
    int m = i >> 8, kk = (i & 255) * 4;
    char4 o;
    o.x = (signed char)(int)fminf(fmaxf(rintf(v.x / s), -128.0f), 127.0f);
    o.y = (signed char)(int)fminf(fmaxf(rintf(v.y / s), -128.0f), 127.0f);
    o.z = (signed char)(int)fminf(fmaxf(rintf(v.z / s), -128.0f), 127.0f);
    o.w = (signed char)(int)fminf(fmaxf(rintf(v.w / s), -128.0f), 127.0f);
    *(char4*)(out + swz(m, kk)) = o;
  }
}

// Fused V: quantize Xv -> codes, transpose per head, permute within each 64-k
// tile to the fused-S^T A-frag order: pos -> k = tp*32 + q*4 + (j<4? j : j+12),
// tp=pos>>5, q=(pos&31)>>3, j=pos&7.
__global__ __launch_bounds__(256) void quantv_t_k(const float* __restrict__ Xv,
                                                  f16* __restrict__ Vt,
                                                  const unsigned* __restrict__ slots) {
  __shared__ f16 T[64][68];
  int tid = threadIdx.x;
  int bh = blockIdx.y, b = bh >> 4, h = bh & 15;
  int k0 = blockIdx.x * 64;
  float s = slot_scale(slots, SLOT_XV, 1.0f);
#pragma unroll
  for (int it = 0; it < 4; ++it) {
    int idx = tid + it * 256;
    int row = idx >> 4, dseg = idx & 15;
    float4 v = *(const float4*)(Xv + ((size_t)(k0 + row) * 2 + b) * 1024 + h * 64 + dseg * 4);
    float xs[4] = {v.x, v.y, v.z, v.w};
    half4 o;
#pragma unroll
    for (int u = 0; u < 4; ++u) {
      float r = rintf(xs[u] / s);
      o[u] = (f16)fminf(fmaxf(r, -128.0f), 127.0f);
    }
    *(half4*)&T[row][dseg * 4] = o;
  }
  __syncthreads();
#pragma unroll
  for (int it = 0; it < 2; ++it) {
    int sdx = tid + it * 256;
    int d = sdx >> 3, j8 = sdx & 7;
    half8 o;
#pragma unroll
    for (int l = 0; l < 8; ++l) {
      int pos = j8 * 8 + l;
      int tp = pos >> 5, pq = (pos & 31) >> 3, jj = pos & 7;
      int k = tp * 32 + pq * 4 + ((jj < 4) ? jj : jj + 12);
      o[l] = T[k][d];
    }
    *(half8*)(Vt + ((size_t)bh * 64 + d) * 2048 + k0 + j8 * 8) = o;
  }
}

// QKV i8 GEMM (exact 2-digit fixed point). M=12288 (q,k,v stacked), N=3072,
// K=1024, BK=64, 512 threads (8 waves, 4m x 2n). Tile-staged operands:
// stage = one contiguous 1KB gl2lds stream per wave; fragment reads are
// chunk*1024 + lane*16 (R12 pattern, zero bank conflicts). Single-barrier
// double-buffer pipeline.
__global__ __launch_bounds__(512) void gemm_qkv_i8_k(const char* __restrict__ A1,
                                                     const char* __restrict__ A2,
                                                     const char* __restrict__ B8,
                                                     const float* __restrict__ bias,
                                                     float* __restrict__ Xout,
                                                     unsigned* __restrict__ slots) {
  __shared__ char As1[2][8192];
  __shared__ char As2[2][8192];
  __shared__ char Bs8[2][8192];
  __shared__ float red[512];

  int tid = threadIdx.x;
  int lane = tid & 63, w = tid >> 6;          // 8 waves
  int wm = w >> 1, wn = w & 1;                // 4 m-slices x 2 n-slices
  int quad = lane >> 4, l15 = lane & 15;
  int t = blockIdx.y >> 5;
  int m0 = (blockIdx.y & 31) * 128;
  int n0 = blockIdx.x * 128;
  size_t aoff = (size_t)t * 4194304;

  const char* a1p = A1 + aoff;
  const char* a2p = A2 + aoff;

  int4v acc1[2][4], acc2[2][4];
#pragma unroll
  for (int i = 0; i < 2; ++i)
#pragma unroll
    for (int j = 0; j < 4; ++j) {
      acc1[i][j] = (int4v){0, 0, 0, 0};
      acc2[i][j] = (int4v){0, 0, 0, 0};
    }

  // wave w stages its 16-row stripe's 1KB chunk: src = stripe base + lane*16
  auto stage = [&](int buf, int kk) __attribute__((always_inline)) {
    size_t ac = ((size_t)((m0 >> 4) + w) << 14) + ((kk >> 6) << 10) + lane * 16;
    size_t bc = ((size_t)((n0 >> 4) + w) << 14) + ((kk >> 6) << 10) + lane * 16;
    gl2lds16(a1p + ac, &As1[buf][w * 1024]);
    gl2lds16(a2p + ac, &As2[buf][w * 1024]);
    gl2lds16(B8 + bc, &Bs8[buf][w * 1024]);
  };

  auto compute = [&](int buf) __attribute__((always_inline)) {
    int4v bf[4];
#pragma unroll
    for (int j = 0; j < 4; ++j)
      bf[j] = *(const int4v*)&Bs8[buf][(wn * 4 + j) * 1024 + lane * 16];
    int4v a1f[2];
#pragma unroll
    for (int i = 0; i < 2; ++i)
      a1f[i] = *(const int4v*)&As1[buf][(wm * 2 + i) * 1024 + lane * 16];
#pragma unroll
    for (int i = 0; i < 2; ++i)
#pragma unroll
      for (int j = 0; j < 4; ++j)
        acc1[i][j] = __builtin_amdgcn_mfma_i32_16x16x64_i8(a1f[i], bf[j], acc1[i][j], 0, 0, 0);
    int4v a2f[2];
#pragma unroll
    for (int i = 0; i < 2; ++i)
      a2f[i] = *(const int4v*)&As2[buf][(wm * 2 + i) * 1024 + lane * 16];
#pragma unroll
    for (int i = 0; i < 2; ++i)
#pragma unroll
      for (int j = 0; j < 4; ++j)
        acc2[i][j] = __builtin_amdgcn_mfma_i32_16x16x64_i8(a2f[i], bf[j], acc2[i][j], 0, 0, 0);
  };

  // Pipeline: one barrier per step; barrier drains only next-tile loads.
  stage(0, 0);
  __syncthreads();
  for (int kt = 0; kt < 7; ++kt) {
    stage(1, (2 * kt + 1) * 64);
    compute(0);
    __syncthreads();
    stage(0, (2 * kt + 2) * 64);
    compute(1);
    __syncthreads();
  }
  stage(1, 960);
  compute(0);
  __syncthreads();
  compute(1);

  float sc = slot_scaleA(slots) * slot_scale(slots, SLOT_WI, 1.0f);
  int colLo = t * 1024;
  float* outT = Xout + aoff;  // per-tensor 4096x1024 fp32 window
  float lmax = 0.f;
#pragma unroll
  for (int i = 0; i < 2; ++i) {
#pragma unroll
    for (int j = 0; j < 4; ++j) {
      int gn = n0 + wn * 64 + j * 16 + l15;
      float bv = bias[gn];
      bool wr = (gn >= colLo && gn < colLo + 1024);
#pragma unroll
      for (int r = 0; r < 4; ++r) {
        int gm = m0 + wm * 32 + i * 16 + quad * 4 + r;
        // |P1| <= 1024*127*128 < 2^24: (float)P1 exact; fmaf keeps it exact.
        float vv = fmaf((float)acc1[i][j][r], 128.0f, (float)acc2[i][j][r]) * sc + bv;
        lmax = fmaxf(lmax, fabsf(vv));
        if (wr) outT[(size_t)gm * 1024 + (gn - colLo)] = vv;
      }
    }
  }
  red[tid] = lmax; __syncthreads();
  for (int sh = 256; sh > 0; sh >>= 1) {
    if (tid < sh) red[tid] = fmaxf(red[tid], red[tid + sh]);
    __syncthreads();
  }
  if (tid == 0) atomicMax(&slots[SLOT_XQ + t], __float_as_uint(red[0]));
}

// Exact i8 output GEMM: Y = (Hint8 @ Wo8^T) * (sH*sW) + bo.
// Same 8-wave/512-thread shape, tile-staged operands, dbuf pipeline.
__global__ __launch_bounds__(512) void gemm_i8out_k(const char* __restrict__ A8,
                                                    const char* __restrict__ B8,
                                                    const float* __restrict__ bias,
                                                    float* __restrict__ out,
                                                    unsigned* __restrict__ slots) {
  __shared__ char As8[2][8192];
  __shared__ char Bs8[2][8192];
  __shared__ float red[512];

  int tid = threadIdx.x;
  int lane = tid & 63, w = tid >> 6;
  int wm = w >> 1, wn = w & 1;
  int quad = lane >> 4, l15 = lane & 15;
  int m0 = blockIdx.y * 128, n0 = blockIdx.x * 128;

  int4v acc[2][4];
#pragma unroll
  for (int i = 0; i < 2; ++i)
#pragma unroll
    for (int j = 0; j < 4; ++j) acc[i][j] = (int4v){0, 0, 0, 0};

  auto stage = [&](int buf, int kk) __attribute__((always_inline)) {
    size_t ac = ((size_t)((m0 >> 4) + w) << 14) + ((kk >> 6) << 10) + lane * 16;
    size_t bc = ((size_t)((n0 >> 4) + w) << 14) + ((kk >> 6) << 10) + lane * 16;
    gl2lds16(A8 + ac, &As8[buf][w * 1024]);
    gl2lds16(B8 + bc, &Bs8[buf][w * 1024]);
  };

  auto compute = [&](int buf) __attribute__((always_inline)) {
    int4v bf[4];
#pragma unroll
    for (int j = 0; j < 4; ++j)
      bf[j] = *(const int4v*)&Bs8[buf][(wn * 4 + j) * 1024 + lane * 16];
    int4v af[2];
#pragma unroll
    for (int i = 0; i < 2; ++i)
      af[i] = *(const int4v*)&As8[buf][(wm * 2 + i) * 1024 + lane * 16];
#pragma unroll
    for (int i = 0; i < 2; ++i)
#pragma unroll
      for (int j = 0; j < 4; ++j)
        acc[i][j] = __builtin_amdgcn_mfma_i32_16x16x64_i8(af[i], bf[j], acc[i][j], 0, 0, 0);
  };

  stage(0, 0);
  __syncthreads();
  for (int kt = 0; kt < 7; ++kt) {
    stage(1, (2 * kt + 1) * 64);
    compute(0);
    __syncthreads();
    stage(0, (2 * kt + 2) * 64);
    compute(1);
    __syncthreads();
  }
  stage(1, 960);
  compute(0);
  __syncthreads();
  compute(1);

  float sc = slot_scale(slots, SLOT_HD, 1.0f) * slot_scale(slots, SLOT_WO, 1.0f);
  float lmax = 0.f;
#pragma unroll
  for (int i = 0; i < 2; ++i) {
#pragma unroll
    for (int j = 0; j < 4; ++j) {
      int gn = n0 + wn * 64 + j * 16 + l15;
      float bv = bias[gn];
#pragma unroll
      for (int r = 0; r < 4; ++r) {
        int gm = m0 + wm * 32 + i * 16 + quad * 4 + r;
        float v = (float)acc[i][j][r] * sc + bv;
        lmax = fmaxf(lmax, fabsf(v));
        out[(size_t)gm * 1024 + gn] = v;
      }
    }
  }
  red[tid] = lmax; __syncthreads();
  for (int sh = 256; sh > 0; sh >>= 1) {
    if (tid < sh) red[tid] = fmaxf(red[tid], red[tid + sh]);
    __syncthreads();
  }
  if (tid == 0) atomicMax(&slots[SLOT_Y], __float_as_uint(red[0]));
}

// Flash attention R10 (unchanged). 128 q-rows/block, 32 q-rows/wave (2x16 subs).
// S^T via mfma(kf, qf); two 16-k S^T blocks fused into one K=32 PV A-frag.
// P never touches LDS. Fixed-offset softmax. V pre-permuted globally.
__global__ __launch_bounds__(256) void attn_k(const f16* __restrict__ Qc,
                                              const f16* __restrict__ Kh,
                                              const f16* __restrict__ Vt,
                                              float* __restrict__ heads,
                                              unsigned* __restrict__ slots) {
  __shared__ f16 Ks[64 * 64];
  __shared__ f16 Vs[64][72];
  __shared__ float lred[4][2][16];
  __shared__ float red[256];

  int tid = threadIdx.x;
  int lane = tid & 63, w = tid >> 6;
  int quad = lane >> 4, l15 = lane & 15;
  int bh = blockIdx.y, b = bh >> 4, h = bh & 15;
  int q0 = blockIdx.x * 128;

  float s1 = slot_scale(slots, SLOT_XQ, 1.0f);
  float sq = slot_scale(slots, SLOT_Q, 0.125f);
  float sk = slot_scale(slots, SLOT_XK, 1.0f);
  float sv = slot_scale(slots, SLOT_XV, 1.0f);
  float cS = sq * sk * 1.44269504088896340736f;
  const float FOFF = 12.0f;  // cancels in P/l

  // Q fragments for both sub-tiles, remap fake_quant(Q/8) inline
  half8 qf[2][2];
#pragma unroll
  for (int s = 0; s < 2; ++s) {
    const f16* qrow = Qc + ((size_t)(q0 + w * 32 + s * 16 + l15) * 2 + b) * 1024 + h * 64;
    half8 qr0 = *(const half8*)(qrow + quad * 8);
    half8 qr1 = *(const half8*)(qrow + 32 + quad * 8);
#pragma unroll
    for (int u = 0; u < 8; ++u) {
      float x0 = ((float)qr0[u] * s1) * 0.125f;
      float x1 = ((float)qr1[u] * s1) * 0.125f;
      qf[s][0][u] = (f16)fminf(fmaxf(rintf(x0 / sq), -128.0f), 127.0f);
      qf[s][1][u] = (f16)fminf(fmaxf(rintf(x1 / sq), -128.0f), 127.0f);
    }
  }

  int ksrow = lane >> 3;
  int ksp = lane & 7;
  int vr0 = tid >> 3, vs0 = (tid & 7) * 8;

  floatx4 oacc[2][4];
#pragma unroll
  for (int s = 0; s < 2; ++s)
#pragma unroll
    for (int d = 0; d < 4; ++d) oacc[s][d] = (floatx4){0.f, 0.f, 0.f, 0.f};
  float lsum[2] = {0.f, 0.f};

  const f16* vbase = Vt + (size_t)bh * 131072;

  for (int kt = 0; kt < 2048; kt += 64) {
    __syncthreads();
#pragma unroll
    for (int t = 0; t < 2; ++t) {
      int r0 = (w * 2 + t) * 8;
      int row = r0 + ksrow;
      int g = ksp ^ (row & 7);
      gl2lds16(Kh + ((size_t)(kt + row) * 2 + b) * 1024 + h * 64 + g * 8, &Ks[r0 * 64]);
    }
    half8 va = *(const half8*)(vbase + (size_t)vr0 * 2048 + kt + vs0);
    half8 vb = *(const half8*)(vbase + (size_t)(vr0 + 32) * 2048 + kt + vs0);
    *(half8*)&Vs[vr0][vs0] = va;
    *(half8*)&Vs[vr0 + 32][vs0] = vb;
    __syncthreads();

    // S^T per 16-k block t; fuse pairs (t=2tp, 2tp+1) into K=32 A-frags
    half8 aph[2][2], apl[2][2];  // [s][tp]
#pragma unroll
    for (int t = 0; t < 4; ++t) {
      int row = t * 16 + l15;
      int g1 = quad ^ (row & 7);
      half8 kf0 = *(half8*)&Ks[row * 64 + g1 * 8];
      half8 kf1 = *(half8*)&Ks[row * 64 + (g1 ^ 4) * 8];
      int tp = t >> 1, hi = (t & 1) * 4;
#pragma unroll
      for (int s = 0; s < 2; ++s) {
        floatx4 sacc = (floatx4){0.f, 0.f, 0.f, 0.f};
        sacc = __builtin_amdgcn_mfma_f32_16x16x32_f16(kf0, qf[s][0], sacc, 0, 0, 0);
        sacc = __builtin_amdgcn_mfma_f32_16x16x32_f16(kf1, qf[s][1], sacc, 0, 0, 0);
        float p0 = __builtin_amdgcn_exp2f(fmaf(sacc[0], cS, -FOFF));
        float p1 = __builtin_amdgcn_exp2f(fmaf(sacc[1], cS, -FOFF));
        float p2 = __builtin_amdgcn_exp2f(fmaf(sacc[2], cS, -FOFF));
        float p3 = __builtin_amdgcn_exp2f(fmaf(sacc[3], cS, -FOFF));
        lsum[s] += (p0 + p1) + (p2 + p3);
        half2v h01 = pack2(p0, p1);
        half2v h23 = pack2(p2, p3);
        half2v l01 = pack2(p0 - (float)h01[0], p1 - (float)h01[1]);
        half2v l23 = pack2(p2 - (float)h23[0], p3 - (float)h23[1]);
        aph[s][tp][hi + 0] = h01[0]; aph[s][tp][hi + 1] = h01[1];
        aph[s][tp][hi + 2] = h23[0]; aph[s][tp][hi + 3] = h23[1];
        apl[s][tp][hi + 0] = l01[0]; apl[s][tp][hi + 1] = l01[1];
        apl[s][tp][hi + 2] = l23[0]; apl[s][tp][hi + 3] = l23[1];
      }
    }

    // PV: per d-block, B-frags are 2 contiguous b128 (tp=0,1); K=32 MFMAs
#pragma unroll
    for (int d = 0; d < 4; ++d) {
      const f16* vsrow = &Vs[d * 16 + l15][0];
      half8 b0 = *(const half8*)(vsrow + quad * 8);        // tp=0: pos quad*8..+7
      half8 b1 = *(const half8*)(vsrow + 32 + quad * 8);   // tp=1
#pragma unroll
      for (int s = 0; s < 2; ++s) {
        oacc[s][d] = __builtin_amdgcn_mfma_f32_16x16x32_f16(aph[s][0], b0, oacc[s][d], 0, 0, 0);
        oacc[s][d] = __builtin_amdgcn_mfma_f32_16x16x32_f16(apl[s][0], b0, oacc[s][d], 0, 0, 0);
        oacc[s][d] = __builtin_amdgcn_mfma_f32_16x16x32_f16(aph[s][1], b1, oacc[s][d], 0, 0, 0);
        oacc[s][d] = __builtin_amdgcn_mfma_f32_16x16x32_f16(apl[s][1], b1, oacc[s][d], 0, 0, 0);
      }
    }
  }

  // l: reduce across the 4 quads, broadcast via LDS (quad<->l15 remap)
#pragma unroll
  for (int s = 0; s < 2; ++s) {
    float l = lsum[s];
    l += __shfl_xor(l, 16);
    l += __shfl_xor(l, 32);
    lred[w][s][l15] = l;
  }
  float linv[2][4];
#pragma unroll
  for (int s = 0; s < 2; ++s)
#pragma unroll
    for (int r = 0; r < 4; ++r) linv[s][r] = sv / lred[w][s][quad * 4 + r];

  float lmax = 0.f;
#pragma unroll
  for (int s = 0; s < 2; ++s)
#pragma unroll
    for (int d = 0; d < 4; ++d)
#pragma unroll
      for (int r = 0; r < 4; ++r) {
        float hv = oacc[s][d][r] * linv[s][r];
        heads[((size_t)(q0 + w * 32 + s * 16 + quad * 4 + r) * 2 + b) * 1024 +
              h * 64 + d * 16 + l15] = hv;
        lmax = fmaxf(lmax, fabsf(hv));
      }
  red[tid] = lmax; __syncthreads();
  for (int sh = 128; sh > 0; sh >>= 1) {
    if (tid < sh) red[tid] = fmaxf(red[tid], red[tid + sh]);
    __syncthreads();
  }
  if (tid == 0) atomicMax(&slots[SLOT_HD], __float_as_uint(red[0]));
}

extern "C" void kernel_launch(void* const* d_in, const int* in_sizes, int n_in,
                              void* d_out, int out_size, void* d_ws, size_t ws_size,
                              hipStream_t stream) {
  (void)in_sizes; (void)n_in; (void)out_size; (void)ws_size;
  const float* query = (const float*)d_in[0];
  const float* key   = (const float*)d_in[1];
  const float* value = (const float*)d_in[2];
  const float* Wi    = (const float*)d_in[3];
  const float* bi    = (const float*)d_in[4];
  const float* Wo    = (const float*)d_in[5];
  const float* bo    = (const float*)d_in[6];
  float* out = (float*)d_out;

  char* p = (char*)d_ws;
  unsigned* slots = (unsigned*)p;            p += 1024;
  char* Wi8 = p;                             p += 3072 * 1024;          // 3 MB
  char* Wo8 = p;                             p += 1024 * 1024;          // 1 MB
  char* A1  = p;                             p += 12288 * 1024;         // 12 MB (q,k,v digit1)
  char* A2  = p;                             p += 12288 * 1024;         // 12 MB (q,k,v digit2)
  float* Hd = (float*)A1;                    // alias: 16 MB spans A1 + first 4MB of A2
  f16* Kint = (f16*)(A2 + 4194304);          // alias: last 8MB of A2 (after GEMM, no Hd overlap)
  float* Xq = (float*)p;                     p += 4096 * 1024 * 4;      // Xq,Xk,Xv contiguous!
  float* Y  = Xq;                            // alias: Xq dead after Qc made
  float* Xk = (float*)p;                     p += 4096 * 1024 * 4;
  f16* Qc   = (f16*)Xk;                      // alias: Xk dead after Kint made (sequential)
  float* Xv = (float*)p;                     p += 4096 * 1024 * 4;
  char* Hint8 = (char*)Xv + 4096 * 1024 * 2; // alias: Xv dead after quantv_t
  f16* Vt   = (f16*)p;                       p += 4096 * 1024 * 2;

  init_slots_k<<<1, 64, 0, stream>>>(slots);
  absmax3_k<<<2560, 256, 0, stream>>>(Wi, Wo, query, key, value, slots);
  quantw_k<<<1024, 256, 0, stream>>>(Wi, Wo, Wi8, Wo8, slots);
  digitize_k<<<2048, 256, 0, stream>>>(query, key, value, A1, A2, slots);

  dim3 gq(24, 96);  // N=3072, M=12288 (q,k,v stacked)
  gemm_qkv_i8_k<<<gq, 512, 0, stream>>>(A1, A2, Wi8, bi, Xq, slots);

  quanti_k<<<1024, 256, 0, stream>>>(Xk, Kint, 1048576, slots, SLOT_XK, -1);
  quanti_k<<<1024, 256, 0, stream>>>(Xq, Qc, 1048576, slots, SLOT_XQ, SLOT_Q);

  dim3 gvt(32, 32);
  quantv_t_k<<<gvt, 256, 0, stream>>>(Xv, Vt, slots);

  dim3 ga(16, 32);
  attn_k<<<ga, 256, 0, stream>>>(Qc, Kint, Vt, Hd, slots);

  quant8_k<<<1024, 256, 0, stream>>>(Hd, Hint8, 1048576, slots, SLOT_HD);

  dim3 g2(8, 32);  // N=1024, M=4096
  gemm_i8out_k<<<g2, 512, 0, stream>>>(Hint8, Wo8, bo, Y, slots);

  quantf_k<<<1024, 256, 0, stream>>>(Y, out, 1048576, slots, SLOT_Y, 1.0f);
}

// Round 9
// 375.895 us; speedup vs baseline: 1.0161x; 1.0161x over previous
//
#include <hip/hip_runtime.h>
#include <math.h>

// MultiheadAttentionQ: W8A8 fake-quant MHA. S=2048, B=2, D=1024, H=16, hd=64.
// R19: R18 + (1) producers of swizzled i8 operands (digitize/quantw/quant8)
// iterate in swizzled-address order: each lane owns one 16B run (16 k of one
// row) -> wave writes 1KB contiguous (R18's scatter cost ~19us); (2) gemm
// epilogue 'red' aliased onto As1[0] (final compute reads half 1 only) ->
// LDS 49152 -> 3 blocks/CU (R18: 51200 -> 2 blocks, Occ 38%); (3) init
// kernel -> hipMemsetAsync, two quanti launches fused. All math and MFMA
// order identical -> bit-identical result (absmax 0.003662109).

typedef _Float16 f16;
typedef _Float16 half8 __attribute__((ext_vector_type(8)));
typedef _Float16 half4 __attribute__((ext_vector_type(4)));
typedef _Float16 half2v __attribute__((ext_vector_type(2)));
typedef __fp16 fp16x2 __attribute__((ext_vector_type(2)));
typedef float floatx4 __attribute__((ext_vector_type(4)));
typedef int int4v __attribute__((ext_vector_type(4)));

#define QMAX 127.0f

#define SLOT_WI 0
#define SLOT_WO 1
#define SLOT_XQ 2
#define SLOT_XK 3
#define SLOT_XV 4
#define SLOT_HD 5
#define SLOT_Y  6
#define SLOT_Q  7
#define SLOT_A  8   // shared absmax of query/key/value (15-bit digitization scale)

__device__ __forceinline__ float slot_scale(const unsigned* slots, int slot, float premul) {
  if (slot < 0) return 1.0f;
  return fmaxf(__uint_as_float(slots[slot]) * premul / QMAX, 1e-8f);
}

__device__ __forceinline__ float slot_scaleA(const unsigned* slots) {
  return fmaxf(__uint_as_float(slots[SLOT_A]) / 16256.0f, 1e-8f);
}

__device__ __forceinline__ void gl2lds16(const void* gsrc, void* ldst) {
  __builtin_amdgcn_global_load_lds((__attribute__((address_space(1))) void*)gsrc,
                                   (__attribute__((address_space(3))) void*)ldst, 16, 0, 0);
}

__device__ __forceinline__ half2v pack2(float a, float b) {
  fp16x2 r = __builtin_amdgcn_cvt_pkrtz(a, b);
  return __builtin_bit_cast(half2v, r);
}

// Tile-staged layout for i8 GEMM operands (K=1024 fixed):
// 16-row stripe x 64-col chunk = 1KB; within: byte (seg*256 + row*16 + b),
// seg=(k>>4)&3, row=m&15, b=k&15. 16B-run index a: addr = a*16,
// a = (m>>4)<<10 | (k>>6)<<6 | ((k>>4)&3)<<4 | (m&15).
// Inverse: m = (a>>10)*16 + (a&15); k0 = (((a>>6)&15)*4 + ((a>>4)&3))*16.

__global__ __launch_bounds__(256) void absmax3_k(const float* __restrict__ Wi,
                                                 const float* __restrict__ Wo,
                                                 const float* __restrict__ q,
                                                 const float* __restrict__ k,
                                                 const float* __restrict__ v,
                                                 unsigned* __restrict__ slots) {
  __shared__ float red[256];
  int tid = threadIdx.x;
  int bid = blockIdx.x;
  const float4* x4;
  int n4, i0, stride, slot;
  if (bid < 768) {
    x4 = (const float4*)Wi; n4 = 786432; i0 = bid * 256 + tid;
    stride = 768 * 256; slot = SLOT_WI;
  } else if (bid < 1024) {
    x4 = (const float4*)Wo; n4 = 262144; i0 = (bid - 768) * 256 + tid;
    stride = 256 * 256; slot = SLOT_WO;
  } else {
    int r = bid - 1024;
    int t = r >> 9;
    x4 = (const float4*)(t == 0 ? q : (t == 1 ? k : v));
    n4 = 1048576; i0 = (r & 511) * 256 + tid;
    stride = 512 * 256; slot = SLOT_A;
  }
  float lmax = 0.f;
  for (int i = i0; i < n4; i += stride) {
    float4 vv = x4[i];
    lmax = fmaxf(lmax, fmaxf(fmaxf(fabsf(vv.x), fabsf(vv.y)), fmaxf(fabsf(vv.z), fabsf(vv.w))));
  }
  red[tid] = lmax; __syncthreads();
  for (int sh = 128; sh > 0; sh >>= 1) {
    if (tid < sh) red[tid] = fmaxf(red[tid], red[tid + sh]);
    __syncthreads();
  }
  if (tid == 0) atomicMax(&slots[slot], __float_as_uint(red[0]));
}

// Weight quant in swizzled-address order: unit a = one 16B run.
// Wi: 196608 units; Wo: 65536 units. Wave writes 1KB contiguous.
__global__ __launch_bounds__(256) void quantw_k(const float* __restrict__ Wi,
                                                const float* __restrict__ Wo,
                                                char* __restrict__ Wi8,
                                                char* __restrict__ Wo8,
                                                const unsigned* __restrict__ slots) {
  int j = blockIdx.x * 256 + threadIdx.x;  // grid covers 262144 exactly
  const float* src; char* dst; float s; int a;
  if (j < 196608) {
    s = slot_scale(slots, SLOT_WI, 1.0f); src = Wi; dst = Wi8; a = j;
  } else {
    s = slot_scale(slots, SLOT_WO, 1.0f); src = Wo; dst = Wo8; a = j - 196608;
  }
  int m = ((a >> 10) << 4) | (a & 15);
  int k0 = ((((a >> 6) & 15) << 2) | ((a >> 4) & 3)) << 4;
  const float4* row = (const float4*)(src + (size_t)m * 1024 + k0);
  char ob[16] __attribute__((aligned(16)));
#pragma unroll
  for (int c = 0; c < 4; ++c) {
    float4 x = row[c];
    float xs[4] = {x.x, x.y, x.z, x.w};
#pragma unroll
    for (int u = 0; u < 4; ++u)
      ob[c * 4 + u] = (signed char)(int)fminf(fmaxf(rintf(xs[u] / s), -128.0f), 127.0f);
  }
  *(int4*)(dst + (size_t)a * 16) = *(const int4*)ob;
}

// q/k/v fp32 -> 2-digit i8 fixed point, swizzled-address iteration order.
__global__ __launch_bounds__(256) void digitize_k(const float* __restrict__ q,
                                                  const float* __restrict__ k,
                                                  const float* __restrict__ v,
                                                  char* __restrict__ A1,
                                                  char* __restrict__ A2,
                                                  const unsigned* __restrict__ slots) {
  float inv = 1.0f / slot_scaleA(slots);
  int j = blockIdx.x * 256 + threadIdx.x;  // grid covers 786432 exactly
  int t = j >> 18;
  int a = j & 262143;
  const float* src = (t == 0 ? q : (t == 1 ? k : v));
  int m = ((a >> 10) << 4) | (a & 15);
  int k0 = ((((a >> 6) & 15) << 2) | ((a >> 4) & 3)) << 4;
  const float4* row = (const float4*)(src + (size_t)m * 1024 + k0);
  char o1[16] __attribute__((aligned(16)));
  char o2[16] __attribute__((aligned(16)));
#pragma unroll
  for (int c = 0; c < 4; ++c) {
    float4 x = row[c];
    float xs[4] = {x.x, x.y, x.z, x.w};
#pragma unroll
    for (int u = 0; u < 4; ++u) {
      float qv = fminf(fmaxf(rintf(xs[u] * inv), -16256.0f), 16256.0f);
      float c1 = rintf(qv * 0.0078125f);
      o1[c * 4 + u] = (signed char)(int)c1;
      o2[c * 4 + u] = (signed char)(int)(qv - 128.0f * c1);
    }
  }
  size_t off = (size_t)t * 4194304 + (size_t)a * 16;
  *(int4*)(A1 + off) = *(const int4*)o1;
  *(int4*)(A2 + off) = *(const int4*)o2;
}

// fp32 -> fp32 fake-quant (n*s).
__global__ __launch_bounds__(256) void quantf_k(const float* __restrict__ in, float* __restrict__ out,
                                                int n4, unsigned* __restrict__ slots,
                                                int sSlot, float premul) {
  float s = slot_scale(slots, sSlot, premul);
  const float4* in4 = (const float4*)in;
  float4* out4 = (float4*)out;
  for (int i = blockIdx.x * 256 + threadIdx.x; i < n4; i += gridDim.x * 256) {
    float4 v = in4[i];
    float xs[4] = {v.x, v.y, v.z, v.w};
#pragma unroll
    for (int u = 0; u < 4; ++u) {
      float r = rintf((xs[u] * premul) / s);
      r = fminf(fmaxf(r, -128.0f), 127.0f);
      xs[u] = r * s;
    }
    out4[i] = make_float4(xs[0], xs[1], xs[2], xs[3]);
  }
}

// Fused: Xk -> Kint f16 codes (blocks < 1024) and Xq -> Qc f16 codes
// (blocks >= 1024, records SLOT_Q absmax). Same math as the old quanti_k.
__global__ __launch_bounds__(256) void quanti2_k(const float* __restrict__ Xk,
                                                 f16* __restrict__ Kint,
                                                 const float* __restrict__ Xq,
                                                 f16* __restrict__ Qc,
                                                 unsigned* __restrict__ slots) {
  __shared__ float red[256];
  bool isQ = blockIdx.x >= 1024;
  const float* in = isQ ? Xq : Xk;
  f16* out = isQ ? Qc : Kint;
  float s = slot_scale(slots, isQ ? SLOT_XQ : SLOT_XK, 1.0f);
  int b = isQ ? blockIdx.x - 1024 : blockIdx.x;
  float lmax = 0.f;
  const float4* in4 = (const float4*)in;
  for (int i = b * 256 + threadIdx.x; i < 1048576; i += 1024 * 256) {
    float4 v = in4[i];
    float xs[4] = {v.x, v.y, v.z, v.w};
    half4 o;
#pragma unroll
    for (int u = 0; u < 4; ++u) {
      float r = rintf(xs[u] / s);
      r = fminf(fmaxf(r, -128.0f), 127.0f);
      o[u] = (f16)r;
      lmax = fmaxf(lmax, fabsf(r));
    }
    *(half4*)(out + (size_t)i * 4) = o;
  }
  if (isQ) {
    int tid = threadIdx.x;
    red[tid] = lmax; __syncthreads();
    for (int sh = 128; sh > 0; sh >>= 1) {
      if (tid < sh) red[tid] = fmaxf(red[tid], red[tid + sh]);
      __syncthreads();
    }
    if (tid == 0) atomicMax(&slots[SLOT_Q], __float_as_uint(red[0] * s));
  }
}

// fp32 -> i8 codes (Hd -> Hint8), swizzled-address iteration order.
__global__ __launch_bounds__(256) void quant8_k(const float* __restrict__ in, char* __restrict__ out,
                                                const unsigned* __restrict__ slots,
                                                int sSlot) {
  float s = slot_scale(slots, sSlot, 1.0f);
  int a = blockIdx.x * 256 + threadIdx.x;  // grid covers 262144 exactly
  int m = ((a >> 10) << 4) | (a & 15);
  int k0 = ((((a >> 6) & 15) << 2) | ((a >> 4) & 3)) << 4;
  const float4* row = (const float4*)(in + (size_t)m * 1024 + k0);
  char ob[16] __attribute__((aligned(16)));
#pragma unroll
  for (int c = 0; c < 4; ++c) {
    float4 x = row[c];
    float xs[4] = {x.x, x.y, x.z, x.w};
#pragma unroll
    for (int u = 0; u < 4; ++u)
      ob[c * 4 + u] = (signed char)(int)fminf(fmaxf(rintf(xs[u] / s), -128.0f), 127.0f);
  }
  *(int4*)(out + (size_t)a * 16) = *(const int4*)ob;
}

// Fused V: quantize Xv -> codes, transpose per head, permute within each 64-k
// tile to the fused-S^T A-frag order: pos -> k = tp*32 + q*4 + (j<4? j : j+12),
// tp=pos>>5, q=(pos&31)>>3, j=pos&7.
__global__ __launch_bounds__(256) void quantv_t_k(const float* __restrict__ Xv,
                                                  f16* __restrict__ Vt,
                                                  const unsigned* __restrict__ slots) {
  __shared__ f16 T[64][68];
  int tid = threadIdx.x;
  int bh = blockIdx.y, b = bh >> 4, h = bh & 15;
  int k0 = blockIdx.x * 64;
  float s = slot_scale(slots, SLOT_XV, 1.0f);
#pragma unroll
  for (int it = 0; it < 4; ++it) {
    int idx = tid + it * 256;
    int row = idx >> 4, dseg = idx & 15;
    float4 v = *(const float4*)(Xv + ((size_t)(k0 + row) * 2 + b) * 1024 + h * 64 + dseg * 4);
    float xs[4] = {v.x, v.y, v.z, v.w};
    half4 o;
#pragma unroll
    for (int u = 0; u < 4; ++u) {
      float r = rintf(xs[u] / s);
      o[u] = (f16)fminf(fmaxf(r, -128.0f), 127.0f);
    }
    *(half4*)&T[row][dseg * 4] = o;
  }
  __syncthreads();
#pragma unroll
  for (int it = 0; it < 2; ++it) {
    int sdx = tid + it * 256;
    int d = sdx >> 3, j8 = sdx & 7;
    half8 o;
#pragma unroll
    for (int l = 0; l < 8; ++l) {
      int pos = j8 * 8 + l;
      int tp = pos >> 5, pq = (pos & 31) >> 3, jj = pos & 7;
      int k = tp * 32 + pq * 4 + ((jj < 4) ? jj : jj + 12);
      o[l] = T[k][d];
    }
    *(half8*)(Vt + ((size_t)bh * 64 + d) * 2048 + k0 + j8 * 8) = o;
  }
}

// QKV i8 GEMM (exact 2-digit fixed point). M=12288 (q,k,v stacked), N=3072,
// K=1024, BK=64, 512 threads (8 waves, 4m x 2n). Tile-staged operands:
// stage = one contiguous 1KB gl2lds stream per wave; fragment reads
// chunk*1024 + lane*16 (zero bank conflicts). Single-barrier dbuf pipeline.
// Epilogue 'red' aliases As1[0] (final compute reads half 1) -> LDS 48KB
// -> 3 blocks/CU.
__global__ __launch_bounds__(512) void gemm_qkv_i8_k(const char* __restrict__ A1,
                                                     const char* __restrict__ A2,
                                                     const char* __restrict__ B8,
                                                     const float* __restrict__ bias,
                                                     float* __restrict__ Xout,
                                                     unsigned* __restrict__ slots) {
  __shared__ char As1[2][8192];
  __shared__ char As2[2][8192];
  __shared__ char Bs8[2][8192];
  float* red = (float*)&As1[0][0];  // 2KB alias; final compute uses As1[1]

  int tid = threadIdx.x;
  int lane = tid & 63, w = tid >> 6;          // 8 waves
  int wm = w >> 1, wn = w & 1;                // 4 m-slices x 2 n-slices
  int quad = lane >> 4, l15 = lane & 15;
  int t = blockIdx.y >> 5;
  int m0 = (blockIdx.y & 31) * 128;
  int n0 = blockIdx.x * 128;
  size_t aoff = (size_t)t * 4194304;

  const char* a1p = A1 + aoff;
  const char* a2p = A2 + aoff;

  int4v acc1[2][4], acc2[2][4];
#pragma unroll
  for (int i = 0; i < 2; ++i)
#pragma unroll
    for (int j = 0; j < 4; ++j) {
      acc1[i][j] = (int4v){0, 0, 0, 0};
      acc2[i][j] = (int4v){0, 0, 0, 0};
    }

  auto stage = [&](int buf, int kk) __attribute__((always_inline)) {
    size_t ac = ((size_t)((m0 >> 4) + w) << 14) + ((kk >> 6) << 10) + lane * 16;
    size_t bc = ((size_t)((n0 >> 4) + w) << 14) + ((kk >> 6) << 10) + lane * 16;
    gl2lds16(a1p + ac, &As1[buf][w * 1024]);
    gl2lds16(a2p + ac, &As2[buf][w * 1024]);
    gl2lds16(B8 + bc, &Bs8[buf][w * 1024]);
  };

  auto compute = [&](int buf) __attribute__((always_inline)) {
    int4v bf[4];
#pragma unroll
    for (int j = 0; j < 4; ++j)
      bf[j] = *(const int4v*)&Bs8[buf][(wn * 4 + j) * 1024 + lane * 16];
    int4v a1f[2];
#pragma unroll
    for (int i = 0; i < 2; ++i)
      a1f[i] = *(const int4v*)&As1[buf][(wm * 2 + i) * 1024 + lane * 16];
#pragma unroll
    for (int i = 0; i < 2; ++i)
#pragma unroll
      for (int j = 0; j < 4; ++j)
        acc1[i][j] = __builtin_amdgcn_mfma_i32_16x16x64_i8(a1f[i], bf[j], acc1[i][j], 0, 0, 0);
    int4v a2f[2];
#pragma unroll
    for (int i = 0; i < 2; ++i)
      a2f[i] = *(const int4v*)&As2[buf][(wm * 2 + i) * 1024 + lane * 16];
#pragma unroll
    for (int i = 0; i < 2; ++i)
#pragma unroll
      for (int j = 0; j < 4; ++j)
        acc2[i][j] = __builtin_amdgcn_mfma_i32_16x16x64_i8(a2f[i], bf[j], acc2[i][j], 0, 0, 0);
  };

  // Pipeline: one barrier per step; barrier drains only next-tile loads.
  stage(0, 0);
  __syncthreads();
  for (int kt = 0; kt < 7; ++kt) {
    stage(1, (2 * kt + 1) * 64);
    compute(0);
    __syncthreads();
    stage(0, (2 * kt + 2) * 64);
    compute(1);
    __syncthreads();
  }
  stage(1, 960);
  compute(0);
  __syncthreads();
  compute(1);

  float sc = slot_scaleA(slots) * slot_scale(slots, SLOT_WI, 1.0f);
  int colLo = t * 1024;
  float* outT = Xout + aoff;  // per-tensor 4096x1024 fp32 window
  float lmax = 0.f;
#pragma unroll
  for (int i = 0; i < 2; ++i) {
#pragma unroll
    for (int j = 0; j < 4; ++j) {
      int gn = n0 + wn * 64 + j * 16 + l15;
      float bv = bias[gn];
      bool wr = (gn >= colLo && gn < colLo + 1024);
#pragma unroll
      for (int r = 0; r < 4; ++r) {
        int gm = m0 + wm * 32 + i * 16 + quad * 4 + r;
        // |P1| <= 1024*127*128 < 2^24: (float)P1 exact; fmaf keeps it exact.
        float vv = fmaf((float)acc1[i][j][r], 128.0f, (float)acc2[i][j][r]) * sc + bv;
        lmax = fmaxf(lmax, fabsf(vv));
        if (wr) outT[(size_t)gm * 1024 + (gn - colLo)] = vv;
      }
    }
  }
  red[tid] = lmax; __syncthreads();
  for (int sh = 256; sh > 0; sh >>= 1) {
    if (tid < sh) red[tid] = fmaxf(red[tid], red[tid + sh]);
    __syncthreads();
  }
  if (tid == 0) atomicMax(&slots[SLOT_XQ + t], __float_as_uint(red[0]));
}

// Exact i8 output GEMM: Y = (Hint8 @ Wo8^T) * (sH*sW) + bo.
// Same 8-wave shape, tile-staged operands, dbuf pipeline, red aliased.
__global__ __launch_bounds__(512) void gemm_i8out_k(const char* __restrict__ A8,
                                                    const char* __restrict__ B8,
                                                    const float* __restrict__ bias,
                                                    float* __restrict__ out,
                                                    unsigned* __restrict__ slots) {
  __shared__ char As8[2][8192];
  __shared__ char Bs8[2][8192];
  float* red = (float*)&As8[0][0];

  int tid = threadIdx.x;
  int lane = tid & 63, w = tid >> 6;
  int wm = w >> 1, wn = w & 1;
  int quad = lane >> 4, l15 = lane & 15;
  int m0 = blockIdx.y * 128, n0 = blockIdx.x * 128;

  int4v acc[2][4];
#pragma unroll
  for (int i = 0; i < 2; ++i)
#pragma unroll
    for (int j = 0; j < 4; ++j) acc[i][j] = (int4v){0, 0, 0, 0};

  auto stage = [&](int buf, int kk) __attribute__((always_inline)) {
    size_t ac = ((size_t)((m0 >> 4) + w) << 14) + ((kk >> 6) << 10) + lane * 16;
    size_t bc = ((size_t)((n0 >> 4) + w) << 14) + ((kk >> 6) << 10) + lane * 16;
    gl2lds16(A8 + ac, &As8[buf][w * 1024]);
    gl2lds16(B8 + bc, &Bs8[buf][w * 1024]);
  };

  auto compute = [&](int buf) __attribute__((always_inline)) {
    int4v bf[4];
#pragma unroll
    for (int j = 0; j < 4; ++j)
      bf[j] = *(const int4v*)&Bs8[buf][(wn * 4 + j) * 1024 + lane * 16];
    int4v af[2];
#pragma unroll
    for (int i = 0; i < 2; ++i)
      af[i] = *(const int4v*)&As8[buf][(wm * 2 + i) * 1024 + lane * 16];
#pragma unroll
    for (int i = 0; i < 2; ++i)
#pragma unroll
      for (int j = 0; j < 4; ++j)
        acc[i][j] = __builtin_amdgcn_mfma_i32_16x16x64_i8(af[i], bf[j], acc[i][j], 0, 0, 0);
  };

  stage(0, 0);
  __syncthreads();
  for (int kt = 0; kt < 7; ++kt) {
    stage(1, (2 * kt + 1) * 64);
    compute(0);
    __syncthreads();
    stage(0, (2 * kt + 2) * 64);
    compute(1);
    __syncthreads();
  }
  stage(1, 960);
  compute(0);
  __syncthreads();
  compute(1);

  float sc = slot_scale(slots, SLOT_HD, 1.0f) * slot_scale(slots, SLOT_WO, 1.0f);
  float lmax = 0.f;
#pragma unroll
  for (int i = 0; i < 2; ++i) {
#pragma unroll
    for (int j = 0; j < 4; ++j) {
      int gn = n0 + wn * 64 + j * 16 + l15;
      float bv = bias[gn];
#pragma unroll
      for (int r = 0; r < 4; ++r) {
        int gm = m0 + wm * 32 + i * 16 + quad * 4 + r;
        float v = (float)acc[i][j][r] * sc + bv;
        lmax = fmaxf(lmax, fabsf(v));
        out[(size_t)gm * 1024 + gn] = v;
      }
    }
  }
  red[tid] = lmax; __syncthreads();
  for (int sh = 256; sh > 0; sh >>= 1) {
    if (tid < sh) red[tid] = fmaxf(red[tid], red[tid + sh]);
    __syncthreads();
  }
  if (tid == 0) atomicMax(&slots[SLOT_Y], __float_as_uint(red[0]));
}

// Flash attention R10 (unchanged). 128 q-rows/block, 32 q-rows/wave (2x16 subs).
// S^T via mfma(kf, qf); two 16-k S^T blocks fused into one K=32 PV A-frag.
// P never touches LDS. Fixed-offset softmax. V pre-permuted globally.
__global__ __launch_bounds__(256) void attn_k(const f16* __restrict__ Qc,
                                              const f16* __restrict__ Kh,
                                              const f16* __restrict__ Vt,
                                              float* __restrict__ heads,
                                              unsigned* __restrict__ slots) {
  __shared__ f16 Ks[64 * 64];
  __shared__ f16 Vs[64][72];
  __shared__ float lred[4][2][16];
  __shared__ float red[256];

  int tid = threadIdx.x;
  int lane = tid & 63, w = tid >> 6;
  int quad = lane >> 4, l15 = lane & 15;
  int bh = blockIdx.y, b = bh >> 4, h = bh & 15;
  int q0 = blockIdx.x * 128;

  float s1 = slot_scale(slots, SLOT_XQ, 1.0f);
  float sq = slot_scale(slots, SLOT_Q, 0.125f);
  float sk = slot_scale(slots, SLOT_XK, 1.0f);
  float sv = slot_scale(slots, SLOT_XV, 1.0f);
  float cS = sq * sk * 1.44269504088896340736f;
  const float FOFF = 12.0f;  // cancels in P/l

  // Q fragments for both sub-tiles, remap fake_quant(Q/8) inline
  half8 qf[2][2];
#pragma unroll
  for (int s = 0; s < 2; ++s) {
    const f16* qrow = Qc + ((size_t)(q0 + w * 32 + s * 16 + l15) * 2 + b) * 1024 + h * 64;
    half8 qr0 = *(const half8*)(qrow + quad * 8);
    half8 qr1 = *(const half8*)(qrow + 32 + quad * 8);
#pragma unroll
    for (int u = 0; u < 8; ++u) {
      float x0 = ((float)qr0[u] * s1) * 0.125f;
      float x1 = ((float)qr1[u] * s1) * 0.125f;
      qf[s][0][u] = (f16)fminf(fmaxf(rintf(x0 / sq), -128.0f), 127.0f);
      qf[s][1][u] = (f16)fminf(fmaxf(rintf(x1 / sq), -128.0f), 127.0f);
    }
  }

  int ksrow = lane >> 3;
  int ksp = lane & 7;
  int vr0 = tid >> 3, vs0 = (tid & 7) * 8;

  floatx4 oacc[2][4];
#pragma unroll
  for (int s = 0; s < 2; ++s)
#pragma unroll
    for (int d = 0; d < 4; ++d) oacc[s][d] = (floatx4){0.f, 0.f, 0.f, 0.f};
  float lsum[2] = {0.f, 0.f};

  const f16* vbase = Vt + (size_t)bh * 131072;

  for (int kt = 0; kt < 2048; kt += 64) {
    __syncthreads();
#pragma unroll
    for (int t = 0; t < 2; ++t) {
      int r0 = (w * 2 + t) * 8;
      int row = r0 + ksrow;
      int g = ksp ^ (row & 7);
      gl2lds16(Kh + ((size_t)(kt + row) * 2 + b) * 1024 + h * 64 + g * 8, &Ks[r0 * 64]);
    }
    half8 va = *(const half8*)(vbase + (size_t)vr0 * 2048 + kt + vs0);
    half8 vb = *(const half8*)(vbase + (size_t)(vr0 + 32) * 2048 + kt + vs0);
    *(half8*)&Vs[vr0][vs0] = va;
    *(half8*)&Vs[vr0 + 32][vs0] = vb;
    __syncthreads();

    // S^T per 16-k block t; fuse pairs (t=2tp, 2tp+1) into K=32 A-frags
    half8 aph[2][2], apl[2][2];  // [s][tp]
#pragma unroll
    for (int t = 0; t < 4; ++t) {
      int row = t * 16 + l15;
      int g1 = quad ^ (row & 7);
      half8 kf0 = *(half8*)&Ks[row * 64 + g1 * 8];
      half8 kf1 = *(half8*)&Ks[row * 64 + (g1 ^ 4) * 8];
      int tp = t >> 1, hi = (t & 1) * 4;
#pragma unroll
      for (int s = 0; s < 2; ++s) {
        floatx4 sacc = (floatx4){0.f, 0.f, 0.f, 0.f};
        sacc = __builtin_amdgcn_mfma_f32_16x16x32_f16(kf0, qf[s][0], sacc, 0, 0, 0);
        sacc = __builtin_amdgcn_mfma_f32_16x16x32_f16(kf1, qf[s][1], sacc, 0, 0, 0);
        float p0 = __builtin_amdgcn_exp2f(fmaf(sacc[0], cS, -FOFF));
        float p1 = __builtin_amdgcn_exp2f(fmaf(sacc[1], cS, -FOFF));
        float p2 = __builtin_amdgcn_exp2f(fmaf(sacc[2], cS, -FOFF));
        float p3 = __builtin_amdgcn_exp2f(fmaf(sacc[3], cS, -FOFF));
        lsum[s] += (p0 + p1) + (p2 + p3);
        half2v h01 = pack2(p0, p1);
        half2v h23 = pack2(p2, p3);
        half2v l01 = pack2(p0 - (float)h01[0], p1 - (float)h01[1]);
        half2v l23 = pack2(p2 - (float)h23[0], p3 - (float)h23[1]);
        aph[s][tp][hi + 0] = h01[0]; aph[s][tp][hi + 1] = h01[1];
        aph[s][tp][hi + 2] = h23[0]; aph[s][tp][hi + 3] = h23[1];
        apl[s][tp][hi + 0] = l01[0]; apl[s][tp][hi + 1] = l01[1];
        apl[s][tp][hi + 2] = l23[0]; apl[s][tp][hi + 3] = l23[1];
      }
    }

    // PV: per d-block, B-frags are 2 contiguous b128 (tp=0,1); K=32 MFMAs
#pragma unroll
    for (int d = 0; d < 4; ++d) {
      const f16* vsrow = &Vs[d * 16 + l15][0];
      half8 b0 = *(const half8*)(vsrow + quad * 8);        // tp=0: pos quad*8..+7
      half8 b1 = *(const half8*)(vsrow + 32 + quad * 8);   // tp=1
#pragma unroll
      for (int s = 0; s < 2; ++s) {
        oacc[s][d] = __builtin_amdgcn_mfma_f32_16x16x32_f16(aph[s][0], b0, oacc[s][d], 0, 0, 0);
        oacc[s][d] = __builtin_amdgcn_mfma_f32_16x16x32_f16(apl[s][0], b0, oacc[s][d], 0, 0, 0);
        oacc[s][d] = __builtin_amdgcn_mfma_f32_16x16x32_f16(aph[s][1], b1, oacc[s][d], 0, 0, 0);
        oacc[s][d] = __builtin_amdgcn_mfma_f32_16x16x32_f16(apl[s][1], b1, oacc[s][d], 0, 0, 0);
      }
    }
  }

  // l: reduce across the 4 quads, broadcast via LDS (quad<->l15 remap)
#pragma unroll
  for (int s = 0; s < 2; ++s) {
    float l = lsum[s];
    l += __shfl_xor(l, 16);
    l += __shfl_xor(l, 32);
    lred[w][s][l15] = l;
  }
  float linv[2][4];
#pragma unroll
  for (int s = 0; s < 2; ++s)
#pragma unroll
    for (int r = 0; r < 4; ++r) linv[s][r] = sv / lred[w][s][quad * 4 + r];

  float lmax = 0.f;
#pragma unroll
  for (int s = 0; s < 2; ++s)
#pragma unroll
    for (int d = 0; d < 4; ++d)
#pragma unroll
      for (int r = 0; r < 4; ++r) {
        float hv = oacc[s][d][r] * linv[s][r];
        heads[((size_t)(q0 + w * 32 + s * 16 + quad * 4 + r) * 2 + b) * 1024 +
              h * 64 + d * 16 + l15] = hv;
        lmax = fmaxf(lmax, fabsf(hv));
      }
  red[tid] = lmax; __syncthreads();
  for (int sh = 128; sh > 0; sh >>= 1) {
    if (tid < sh) red[tid] = fmaxf(red[tid], red[tid + sh]);
    __syncthreads();
  }
  if (tid == 0) atomicMax(&slots[SLOT_HD], __float_as_uint(red[0]));
}

extern "C" void kernel_launch(void* const* d_in, const int* in_sizes, int n_in,
                              void* d_out, int out_size, void* d_ws, size_t ws_size,
                              hipStream_t stream) {
  (void)in_sizes; (void)n_in; (void)out_size; (void)ws_size;
  const float* query = (const float*)d_in[0];
  const float* key   = (const float*)d_in[1];
  const float* value = (const float*)d_in[2];
  const float* Wi    = (const float*)d_in[3];
  const float* bi    = (const float*)d_in[4];
  const float* Wo    = (const float*)d_in[5];
  const float* bo    = (const float*)d_in[6];
  float* out = (float*)d_out;

  char* p = (char*)d_ws;
  unsigned* slots = (unsigned*)p;            p += 1024;
  char* Wi8 = p;                             p += 3072 * 1024;          // 3 MB
  char* Wo8 = p;                             p += 1024 * 1024;          // 1 MB
  char* A1  = p;                             p += 12288 * 1024;         // 12 MB (q,k,v digit1)
  char* A2  = p;                             p += 12288 * 1024;         // 12 MB (q,k,v digit2)
  float* Hd = (float*)A1;                    // alias: 16 MB spans A1 + first 4MB of A2
  f16* Kint = (f16*)(A2 + 4194304);          // alias: last 8MB of A2 (after GEMM, no Hd overlap)
  float* Xq = (float*)p;                     p += 4096 * 1024 * 4;      // Xq,Xk,Xv contiguous!
  float* Y  = Xq;                            // alias: Xq dead after Qc made
  float* Xk = (float*)p;                     p += 4096 * 1024 * 4;
  f16* Qc   = (f16*)Xk;                      // alias: Xk dead after Kint made (sequential)
  float* Xv = (float*)p;                     p += 4096 * 1024 * 4;
  char* Hint8 = (char*)Xv + 4096 * 1024 * 2; // alias: Xv dead after quantv_t
  f16* Vt   = (f16*)p;                       p += 4096 * 1024 * 2;

  hipMemsetAsync(slots, 0, 64, stream);
  absmax3_k<<<2560, 256, 0, stream>>>(Wi, Wo, query, key, value, slots);
  quantw_k<<<1024, 256, 0, stream>>>(Wi, Wo, Wi8, Wo8, slots);
  digitize_k<<<3072, 256, 0, stream>>>(query, key, value, A1, A2, slots);

  dim3 gq(24, 96);  // N=3072, M=12288 (q,k,v stacked)
  gemm_qkv_i8_k<<<gq, 512, 0, stream>>>(A1, A2, Wi8, bi, Xq, slots);

  quanti2_k<<<2048, 256, 0, stream>>>(Xk, Kint, Xq, Qc, slots);

  dim3 gvt(32, 32);
  quantv_t_k<<<gvt, 256, 0, stream>>>(Xv, Vt, slots);

  dim3 ga(16, 32);
  attn_k<<<ga, 256, 0, stream>>>(Qc, Kint, Vt, Hd, slots);

  quant8_k<<<1024, 256, 0, stream>>>(Hd, Hint8, slots, SLOT_HD);

  dim3 g2(8, 32);  // N=1024, M=4096
  gemm_i8out_k<<<g2, 512, 0, stream>>>(Hint8, Wo8, bo, Y, slots);

  quantf_k<<<1024, 256, 0, stream>>>(Y, out, 1048576, slots, SLOT_Y, 1.0f);
}

// Round 10
// 356.466 us; speedup vs baseline: 1.0715x; 1.0545x over previous
//
#include <hip/hip_runtime.h>
#include <math.h>

// MultiheadAttentionQ: W8A8 fake-quant MHA. S=2048, B=2, D=1024, H=16, hd=64.
// R20: R19 + single-barrier double-buffered pipeline in attn_k (the R15/R17
// recipe applied to attention). Old: 2 barriers/iter, vmcnt(0) drain exposed
// K/V load latency 32x (attn 77us, Occ 19%, MfmaUtil 27%). New: Ks[2]/Vs[2];
// per iter stage K(t+1) via gl2lds + write V(t+1) from regs + issue V(t+2)
// loads BEFORE compute(t); one __syncthreads drains loads issued a full
// compute phase earlier (free). Compute body & MFMA order untouched ->
// bit-identical (absmax 0.003662109). All other kernels frozen from R19.

typedef _Float16 f16;
typedef _Float16 half8 __attribute__((ext_vector_type(8)));
typedef _Float16 half4 __attribute__((ext_vector_type(4)));
typedef _Float16 half2v __attribute__((ext_vector_type(2)));
typedef __fp16 fp16x2 __attribute__((ext_vector_type(2)));
typedef float floatx4 __attribute__((ext_vector_type(4)));
typedef int int4v __attribute__((ext_vector_type(4)));

#define QMAX 127.0f

#define SLOT_WI 0
#define SLOT_WO 1
#define SLOT_XQ 2
#define SLOT_XK 3
#define SLOT_XV 4
#define SLOT_HD 5
#define SLOT_Y  6
#define SLOT_Q  7
#define SLOT_A  8   // shared absmax of query/key/value (15-bit digitization scale)

__device__ __forceinline__ float slot_scale(const unsigned* slots, int slot, float premul) {
  if (slot < 0) return 1.0f;
  return fmaxf(__uint_as_float(slots[slot]) * premul / QMAX, 1e-8f);
}

__device__ __forceinline__ float slot_scaleA(const unsigned* slots) {
  return fmaxf(__uint_as_float(slots[SLOT_A]) / 16256.0f, 1e-8f);
}

__device__ __forceinline__ void gl2lds16(const void* gsrc, void* ldst) {
  __builtin_amdgcn_global_load_lds((__attribute__((address_space(1))) void*)gsrc,
                                   (__attribute__((address_space(3))) void*)ldst, 16, 0, 0);
}

__device__ __forceinline__ half2v pack2(float a, float b) {
  fp16x2 r = __builtin_amdgcn_cvt_pkrtz(a, b);
  return __builtin_bit_cast(half2v, r);
}

// Tile-staged layout for i8 GEMM operands (K=1024 fixed):
// 16-row stripe x 64-col chunk = 1KB; within: byte (seg*256 + row*16 + b),
// seg=(k>>4)&3, row=m&15, b=k&15. 16B-run index a: addr = a*16,
// a = (m>>4)<<10 | (k>>6)<<6 | ((k>>4)&3)<<4 | (m&15).
// Inverse: m = (a>>10)*16 + (a&15); k0 = (((a>>6)&15)*4 + ((a>>4)&3))*16.

__global__ __launch_bounds__(256) void absmax3_k(const float* __restrict__ Wi,
                                                 const float* __restrict__ Wo,
                                                 const float* __restrict__ q,
                                                 const float* __restrict__ k,
                                                 const float* __restrict__ v,
                                                 unsigned* __restrict__ slots) {
  __shared__ float red[256];
  int tid = threadIdx.x;
  int bid = blockIdx.x;
  const float4* x4;
  int n4, i0, stride, slot;
  if (bid < 768) {
    x4 = (const float4*)Wi; n4 = 786432; i0 = bid * 256 + tid;
    stride = 768 * 256; slot = SLOT_WI;
  } else if (bid < 1024) {
    x4 = (const float4*)Wo; n4 = 262144; i0 = (bid - 768) * 256 + tid;
    stride = 256 * 256; slot = SLOT_WO;
  } else {
    int r = bid - 1024;
    int t = r >> 9;
    x4 = (const float4*)(t == 0 ? q : (t == 1 ? k : v));
    n4 = 1048576; i0 = (r & 511) * 256 + tid;
    stride = 512 * 256; slot = SLOT_A;
  }
  float lmax = 0.f;
  for (int i = i0; i < n4; i += stride) {
    float4 vv = x4[i];
    lmax = fmaxf(lmax, fmaxf(fmaxf(fabsf(vv.x), fabsf(vv.y)), fmaxf(fabsf(vv.z), fabsf(vv.w))));
  }
  red[tid] = lmax; __syncthreads();
  for (int sh = 128; sh > 0; sh >>= 1) {
    if (tid < sh) red[tid] = fmaxf(red[tid], red[tid + sh]);
    __syncthreads();
  }
  if (tid == 0) atomicMax(&slots[slot], __float_as_uint(red[0]));
}

// Weight quant in swizzled-address order: unit a = one 16B run.
// Wi: 196608 units; Wo: 65536 units. Wave writes 1KB contiguous.
__global__ __launch_bounds__(256) void quantw_k(const float* __restrict__ Wi,
                                                const float* __restrict__ Wo,
                                                char* __restrict__ Wi8,
                                                char* __restrict__ Wo8,
                                                const unsigned* __restrict__ slots) {
  int j = blockIdx.x * 256 + threadIdx.x;  // grid covers 262144 exactly
  const float* src; char* dst; float s; int a;
  if (j < 196608) {
    s = slot_scale(slots, SLOT_WI, 1.0f); src = Wi; dst = Wi8; a = j;
  } else {
    s = slot_scale(slots, SLOT_WO, 1.0f); src = Wo; dst = Wo8; a = j - 196608;
  }
  int m = ((a >> 10) << 4) | (a & 15);
  int k0 = ((((a >> 6) & 15) << 2) | ((a >> 4) & 3)) << 4;
  const float4* row = (const float4*)(src + (size_t)m * 1024 + k0);
  char ob[16] __attribute__((aligned(16)));
#pragma unroll
  for (int c = 0; c < 4; ++c) {
    float4 x = row[c];
    float xs[4] = {x.x, x.y, x.z, x.w};
#pragma unroll
    for (int u = 0; u < 4; ++u)
      ob[c * 4 + u] = (signed char)(int)fminf(fmaxf(rintf(xs[u] / s), -128.0f), 127.0f);
  }
  *(int4*)(dst + (size_t)a * 16) = *(const int4*)ob;
}

// q/k/v fp32 -> 2-digit i8 fixed point, swizzled-address iteration order.
__global__ __launch_bounds__(256) void digitize_k(const float* __restrict__ q,
                                                  const float* __restrict__ k,
                                                  const float* __restrict__ v,
                                                  char* __restrict__ A1,
                                                  char* __restrict__ A2,
                                                  const unsigned* __restrict__ slots) {
  float inv = 1.0f / slot_scaleA(slots);
  int j = blockIdx.x * 256 + threadIdx.x;  // grid covers 786432 exactly
  int t = j >> 18;
  int a = j & 262143;
  const float* src = (t == 0 ? q : (t == 1 ? k : v));
  int m = ((a >> 10) << 4) | (a & 15);
  int k0 = ((((a >> 6) & 15) << 2) | ((a >> 4) & 3)) << 4;
  const float4* row = (const float4*)(src + (size_t)m * 1024 + k0);
  char o1[16] __attribute__((aligned(16)));
  char o2[16] __attribute__((aligned(16)));
#pragma unroll
  for (int c = 0; c < 4; ++c) {
    float4 x = row[c];
    float xs[4] = {x.x, x.y, x.z, x.w};
#pragma unroll
    for (int u = 0; u < 4; ++u) {
      float qv = fminf(fmaxf(rintf(xs[u] * inv), -16256.0f), 16256.0f);
      float c1 = rintf(qv * 0.0078125f);
      o1[c * 4 + u] = (signed char)(int)c1;
      o2[c * 4 + u] = (signed char)(int)(qv - 128.0f * c1);
    }
  }
  size_t off = (size_t)t * 4194304 + (size_t)a * 16;
  *(int4*)(A1 + off) = *(const int4*)o1;
  *(int4*)(A2 + off) = *(const int4*)o2;
}

// fp32 -> fp32 fake-quant (n*s).
__global__ __launch_bounds__(256) void quantf_k(const float* __restrict__ in, float* __restrict__ out,
                                                int n4, unsigned* __restrict__ slots,
                                                int sSlot, float premul) {
  float s = slot_scale(slots, sSlot, premul);
  const float4* in4 = (const float4*)in;
  float4* out4 = (float4*)out;
  for (int i = blockIdx.x * 256 + threadIdx.x; i < n4; i += gridDim.x * 256) {
    float4 v = in4[i];
    float xs[4] = {v.x, v.y, v.z, v.w};
#pragma unroll
    for (int u = 0; u < 4; ++u) {
      float r = rintf((xs[u] * premul) / s);
      r = fminf(fmaxf(r, -128.0f), 127.0f);
      xs[u] = r * s;
    }
    out4[i] = make_float4(xs[0], xs[1], xs[2], xs[3]);
  }
}

// Fused: Xk -> Kint f16 codes (blocks < 1024) and Xq -> Qc f16 codes
// (blocks >= 1024, records SLOT_Q absmax).
__global__ __launch_bounds__(256) void quanti2_k(const float* __restrict__ Xk,
                                                 f16* __restrict__ Kint,
                                                 const float* __restrict__ Xq,
                                                 f16* __restrict__ Qc,
                                                 unsigned* __restrict__ slots) {
  __shared__ float red[256];
  bool isQ = blockIdx.x >= 1024;
  const float* in = isQ ? Xq : Xk;
  f16* out = isQ ? Qc : Kint;
  float s = slot_scale(slots, isQ ? SLOT_XQ : SLOT_XK, 1.0f);
  int b = isQ ? blockIdx.x - 1024 : blockIdx.x;
  float lmax = 0.f;
  const float4* in4 = (const float4*)in;
  for (int i = b * 256 + threadIdx.x; i < 1048576; i += 1024 * 256) {
    float4 v = in4[i];
    float xs[4] = {v.x, v.y, v.z, v.w};
    half4 o;
#pragma unroll
    for (int u = 0; u < 4; ++u) {
      float r = rintf(xs[u] / s);
      r = fminf(fmaxf(r, -128.0f), 127.0f);
      o[u] = (f16)r;
      lmax = fmaxf(lmax, fabsf(r));
    }
    *(half4*)(out + (size_t)i * 4) = o;
  }
  if (isQ) {
    int tid = threadIdx.x;
    red[tid] = lmax; __syncthreads();
    for (int sh = 128; sh > 0; sh >>= 1) {
      if (tid < sh) red[tid] = fmaxf(red[tid], red[tid + sh]);
      __syncthreads();
    }
    if (tid == 0) atomicMax(&slots[SLOT_Q], __float_as_uint(red[0] * s));
  }
}

// fp32 -> i8 codes (Hd -> Hint8), swizzled-address iteration order.
__global__ __launch_bounds__(256) void quant8_k(const float* __restrict__ in, char* __restrict__ out,
                                                const unsigned* __restrict__ slots,
                                                int sSlot) {
  float s = slot_scale(slots, sSlot, 1.0f);
  int a = blockIdx.x * 256 + threadIdx.x;  // grid covers 262144 exactly
  int m = ((a >> 10) << 4) | (a & 15);
  int k0 = ((((a >> 6) & 15) << 2) | ((a >> 4) & 3)) << 4;
  const float4* row = (const float4*)(in + (size_t)m * 1024 + k0);
  char ob[16] __attribute__((aligned(16)));
#pragma unroll
  for (int c = 0; c < 4; ++c) {
    float4 x = row[c];
    float xs[4] = {x.x, x.y, x.z, x.w};
#pragma unroll
    for (int u = 0; u < 4; ++u)
      ob[c * 4 + u] = (signed char)(int)fminf(fmaxf(rintf(xs[u] / s), -128.0f), 127.0f);
  }
  *(int4*)(out + (size_t)a * 16) = *(const int4*)ob;
}

// Fused V: quantize Xv -> codes, transpose per head, permute within each 64-k
// tile to the fused-S^T A-frag order: pos -> k = tp*32 + q*4 + (j<4? j : j+12),
// tp=pos>>5, q=(pos&31)>>3, j=pos&7.
__global__ __launch_bounds__(256) void quantv_t_k(const float* __restrict__ Xv,
                                                  f16* __restrict__ Vt,
                                                  const unsigned* __restrict__ slots) {
  __shared__ f16 T[64][68];
  int tid = threadIdx.x;
  int bh = blockIdx.y, b = bh >> 4, h = bh & 15;
  int k0 = blockIdx.x * 64;
  float s = slot_scale(slots, SLOT_XV, 1.0f);
#pragma unroll
  for (int it = 0; it < 4; ++it) {
    int idx = tid + it * 256;
    int row = idx >> 4, dseg = idx & 15;
    float4 v = *(const float4*)(Xv + ((size_t)(k0 + row) * 2 + b) * 1024 + h * 64 + dseg * 4);
    float xs[4] = {v.x, v.y, v.z, v.w};
    half4 o;
#pragma unroll
    for (int u = 0; u < 4; ++u) {
      float r = rintf(xs[u] / s);
      o[u] = (f16)fminf(fmaxf(r, -128.0f), 127.0f);
    }
    *(half4*)&T[row][dseg * 4] = o;
  }
  __syncthreads();
#pragma unroll
  for (int it = 0; it < 2; ++it) {
    int sdx = tid + it * 256;
    int d = sdx >> 3, j8 = sdx & 7;
    half8 o;
#pragma unroll
    for (int l = 0; l < 8; ++l) {
      int pos = j8 * 8 + l;
      int tp = pos >> 5, pq = (pos & 31) >> 3, jj = pos & 7;
      int k = tp * 32 + pq * 4 + ((jj < 4) ? jj : jj + 12);
      o[l] = T[k][d];
    }
    *(half8*)(Vt + ((size_t)bh * 64 + d) * 2048 + k0 + j8 * 8) = o;
  }
}

// QKV i8 GEMM (exact 2-digit fixed point). M=12288 (q,k,v stacked), N=3072,
// K=1024, BK=64, 512 threads (8 waves, 4m x 2n). Tile-staged operands;
// fragment reads chunk*1024 + lane*16 (zero bank conflicts). Single-barrier
// dbuf pipeline. Epilogue 'red' aliases As1[0].
__global__ __launch_bounds__(512) void gemm_qkv_i8_k(const char* __restrict__ A1,
                                                     const char* __restrict__ A2,
                                                     const char* __restrict__ B8,
                                                     const float* __restrict__ bias,
                                                     float* __restrict__ Xout,
                                                     unsigned* __restrict__ slots) {
  __shared__ char As1[2][8192];
  __shared__ char As2[2][8192];
  __shared__ char Bs8[2][8192];
  float* red = (float*)&As1[0][0];  // 2KB alias; final compute uses As1[1]

  int tid = threadIdx.x;
  int lane = tid & 63, w = tid >> 6;          // 8 waves
  int wm = w >> 1, wn = w & 1;                // 4 m-slices x 2 n-slices
  int quad = lane >> 4, l15 = lane & 15;
  int t = blockIdx.y >> 5;
  int m0 = (blockIdx.y & 31) * 128;
  int n0 = blockIdx.x * 128;
  size_t aoff = (size_t)t * 4194304;

  const char* a1p = A1 + aoff;
  const char* a2p = A2 + aoff;

  int4v acc1[2][4], acc2[2][4];
#pragma unroll
  for (int i = 0; i < 2; ++i)
#pragma unroll
    for (int j = 0; j < 4; ++j) {
      acc1[i][j] = (int4v){0, 0, 0, 0};
      acc2[i][j] = (int4v){0, 0, 0, 0};
    }

  auto stage = [&](int buf, int kk) __attribute__((always_inline)) {
    size_t ac = ((size_t)((m0 >> 4) + w) << 14) + ((kk >> 6) << 10) + lane * 16;
    size_t bc = ((size_t)((n0 >> 4) + w) << 14) + ((kk >> 6) << 10) + lane * 16;
    gl2lds16(a1p + ac, &As1[buf][w * 1024]);
    gl2lds16(a2p + ac, &As2[buf][w * 1024]);
    gl2lds16(B8 + bc, &Bs8[buf][w * 1024]);
  };

  auto compute = [&](int buf) __attribute__((always_inline)) {
    int4v bf[4];
#pragma unroll
    for (int j = 0; j < 4; ++j)
      bf[j] = *(const int4v*)&Bs8[buf][(wn * 4 + j) * 1024 + lane * 16];
    int4v a1f[2];
#pragma unroll
    for (int i = 0; i < 2; ++i)
      a1f[i] = *(const int4v*)&As1[buf][(wm * 2 + i) * 1024 + lane * 16];
#pragma unroll
    for (int i = 0; i < 2; ++i)
#pragma unroll
      for (int j = 0; j < 4; ++j)
        acc1[i][j] = __builtin_amdgcn_mfma_i32_16x16x64_i8(a1f[i], bf[j], acc1[i][j], 0, 0, 0);
    int4v a2f[2];
#pragma unroll
    for (int i = 0; i < 2; ++i)
      a2f[i] = *(const int4v*)&As2[buf][(wm * 2 + i) * 1024 + lane * 16];
#pragma unroll
    for (int i = 0; i < 2; ++i)
#pragma unroll
      for (int j = 0; j < 4; ++j)
        acc2[i][j] = __builtin_amdgcn_mfma_i32_16x16x64_i8(a2f[i], bf[j], acc2[i][j], 0, 0, 0);
  };

  stage(0, 0);
  __syncthreads();
  for (int kt = 0; kt < 7; ++kt) {
    stage(1, (2 * kt + 1) * 64);
    compute(0);
    __syncthreads();
    stage(0, (2 * kt + 2) * 64);
    compute(1);
    __syncthreads();
  }
  stage(1, 960);
  compute(0);
  __syncthreads();
  compute(1);

  float sc = slot_scaleA(slots) * slot_scale(slots, SLOT_WI, 1.0f);
  int colLo = t * 1024;
  float* outT = Xout + aoff;  // per-tensor 4096x1024 fp32 window
  float lmax = 0.f;
#pragma unroll
  for (int i = 0; i < 2; ++i) {
#pragma unroll
    for (int j = 0; j < 4; ++j) {
      int gn = n0 + wn * 64 + j * 16 + l15;
      float bv = bias[gn];
      bool wr = (gn >= colLo && gn < colLo + 1024);
#pragma unroll
      for (int r = 0; r < 4; ++r) {
        int gm = m0 + wm * 32 + i * 16 + quad * 4 + r;
        // |P1| <= 1024*127*128 < 2^24: (float)P1 exact; fmaf keeps it exact.
        float vv = fmaf((float)acc1[i][j][r], 128.0f, (float)acc2[i][j][r]) * sc + bv;
        lmax = fmaxf(lmax, fabsf(vv));
        if (wr) outT[(size_t)gm * 1024 + (gn - colLo)] = vv;
      }
    }
  }
  red[tid] = lmax; __syncthreads();
  for (int sh = 256; sh > 0; sh >>= 1) {
    if (tid < sh) red[tid] = fmaxf(red[tid], red[tid + sh]);
    __syncthreads();
  }
  if (tid == 0) atomicMax(&slots[SLOT_XQ + t], __float_as_uint(red[0]));
}

// Exact i8 output GEMM: Y = (Hint8 @ Wo8^T) * (sH*sW) + bo.
__global__ __launch_bounds__(512) void gemm_i8out_k(const char* __restrict__ A8,
                                                    const char* __restrict__ B8,
                                                    const float* __restrict__ bias,
                                                    float* __restrict__ out,
                                                    unsigned* __restrict__ slots) {
  __shared__ char As8[2][8192];
  __shared__ char Bs8[2][8192];
  float* red = (float*)&As8[0][0];

  int tid = threadIdx.x;
  int lane = tid & 63, w = tid >> 6;
  int wm = w >> 1, wn = w & 1;
  int quad = lane >> 4, l15 = lane & 15;
  int m0 = blockIdx.y * 128, n0 = blockIdx.x * 128;

  int4v acc[2][4];
#pragma unroll
  for (int i = 0; i < 2; ++i)
#pragma unroll
    for (int j = 0; j < 4; ++j) acc[i][j] = (int4v){0, 0, 0, 0};

  auto stage = [&](int buf, int kk) __attribute__((always_inline)) {
    size_t ac = ((size_t)((m0 >> 4) + w) << 14) + ((kk >> 6) << 10) + lane * 16;
    size_t bc = ((size_t)((n0 >> 4) + w) << 14) + ((kk >> 6) << 10) + lane * 16;
    gl2lds16(A8 + ac, &As8[buf][w * 1024]);
    gl2lds16(B8 + bc, &Bs8[buf][w * 1024]);
  };

  auto compute = [&](int buf) __attribute__((always_inline)) {
    int4v bf[4];
#pragma unroll
    for (int j = 0; j < 4; ++j)
      bf[j] = *(const int4v*)&Bs8[buf][(wn * 4 + j) * 1024 + lane * 16];
    int4v af[2];
#pragma unroll
    for (int i = 0; i < 2; ++i)
      af[i] = *(const int4v*)&As8[buf][(wm * 2 + i) * 1024 + lane * 16];
#pragma unroll
    for (int i = 0; i < 2; ++i)
#pragma unroll
      for (int j = 0; j < 4; ++j)
        acc[i][j] = __builtin_amdgcn_mfma_i32_16x16x64_i8(af[i], bf[j], acc[i][j], 0, 0, 0);
  };

  stage(0, 0);
  __syncthreads();
  for (int kt = 0; kt < 7; ++kt) {
    stage(1, (2 * kt + 1) * 64);
    compute(0);
    __syncthreads();
    stage(0, (2 * kt + 2) * 64);
    compute(1);
    __syncthreads();
  }
  stage(1, 960);
  compute(0);
  __syncthreads();
  compute(1);

  float sc = slot_scale(slots, SLOT_HD, 1.0f) * slot_scale(slots, SLOT_WO, 1.0f);
  float lmax = 0.f;
#pragma unroll
  for (int i = 0; i < 2; ++i) {
#pragma unroll
    for (int j = 0; j < 4; ++j) {
      int gn = n0 + wn * 64 + j * 16 + l15;
      float bv = bias[gn];
#pragma unroll
      for (int r = 0; r < 4; ++r) {
        int gm = m0 + wm * 32 + i * 16 + quad * 4 + r;
        float v = (float)acc[i][j][r] * sc + bv;
        lmax = fmaxf(lmax, fabsf(v));
        out[(size_t)gm * 1024 + gn] = v;
      }
    }
  }
  red[tid] = lmax; __syncthreads();
  for (int sh = 256; sh > 0; sh >>= 1) {
    if (tid < sh) red[tid] = fmaxf(red[tid], red[tid + sh]);
    __syncthreads();
  }
  if (tid == 0) atomicMax(&slots[SLOT_Y], __float_as_uint(red[0]));
}

// Flash attention R20: double-buffered Ks/Vs, ONE barrier per K/V tile.
// Per iter: stage K(t+1) (gl2lds) + write V(t+1) from regs + issue V(t+2)
// loads, then compute(t); barrier drains loads issued a compute-phase ago.
// Compute body identical to R10 (bit-identical math).
__global__ __launch_bounds__(256) void attn_k(const f16* __restrict__ Qc,
                                              const f16* __restrict__ Kh,
                                              const f16* __restrict__ Vt,
                                              float* __restrict__ heads,
                                              unsigned* __restrict__ slots) {
  __shared__ f16 Ks[2][64 * 64];
  __shared__ f16 Vs[2][64][72];
  __shared__ float lred[4][2][16];
  __shared__ float red[256];

  int tid = threadIdx.x;
  int lane = tid & 63, w = tid >> 6;
  int quad = lane >> 4, l15 = lane & 15;
  int bh = blockIdx.y, b = bh >> 4, h = bh & 15;
  int q0 = blockIdx.x * 128;

  float s1 = slot_scale(slots, SLOT_XQ, 1.0f);
  float sq = slot_scale(slots, SLOT_Q, 0.125f);
  float sk = slot_scale(slots, SLOT_XK, 1.0f);
  float sv = slot_scale(slots, SLOT_XV, 1.0f);
  float cS = sq * sk * 1.44269504088896340736f;
  const float FOFF = 12.0f;  // cancels in P/l

  // Q fragments for both sub-tiles, remap fake_quant(Q/8) inline
  half8 qf[2][2];
#pragma unroll
  for (int s = 0; s < 2; ++s) {
    const f16* qrow = Qc + ((size_t)(q0 + w * 32 + s * 16 + l15) * 2 + b) * 1024 + h * 64;
    half8 qr0 = *(const half8*)(qrow + quad * 8);
    half8 qr1 = *(const half8*)(qrow + 32 + quad * 8);
#pragma unroll
    for (int u = 0; u < 8; ++u) {
      float x0 = ((float)qr0[u] * s1) * 0.125f;
      float x1 = ((float)qr1[u] * s1) * 0.125f;
      qf[s][0][u] = (f16)fminf(fmaxf(rintf(x0 / sq), -128.0f), 127.0f);
      qf[s][1][u] = (f16)fminf(fmaxf(rintf(x1 / sq), -128.0f), 127.0f);
    }
  }

  int ksrow = lane >> 3;
  int ksp = lane & 7;
  int vr0 = tid >> 3, vs0 = (tid & 7) * 8;

  floatx4 oacc[2][4];
#pragma unroll
  for (int s = 0; s < 2; ++s)
#pragma unroll
    for (int d = 0; d < 4; ++d) oacc[s][d] = (floatx4){0.f, 0.f, 0.f, 0.f};
  float lsum[2] = {0.f, 0.f};

  const f16* vbase = Vt + (size_t)bh * 131072;
  half8 va, vb;

  auto stageK = [&](int bf, int kt) __attribute__((always_inline)) {
#pragma unroll
    for (int t = 0; t < 2; ++t) {
      int r0 = (w * 2 + t) * 8;
      int row = r0 + ksrow;
      int g = ksp ^ (row & 7);
      gl2lds16(Kh + ((size_t)(kt + row) * 2 + b) * 1024 + h * 64 + g * 8, &Ks[bf][r0 * 64]);
    }
  };
  auto loadV = [&](int kt) __attribute__((always_inline)) {
    va = *(const half8*)(vbase + (size_t)vr0 * 2048 + kt + vs0);
    vb = *(const half8*)(vbase + (size_t)(vr0 + 32) * 2048 + kt + vs0);
  };
  auto writeV = [&](int bf) __attribute__((always_inline)) {
    *(half8*)&Vs[bf][vr0][vs0] = va;
    *(half8*)&Vs[bf][vr0 + 32][vs0] = vb;
  };

  auto compute = [&](int bf) __attribute__((always_inline)) {
    // S^T per 16-k block t; fuse pairs (t=2tp, 2tp+1) into K=32 A-frags
    half8 aph[2][2], apl[2][2];  // [s][tp]
#pragma unroll
    for (int t = 0; t < 4; ++t) {
      int row = t * 16 + l15;
      int g1 = quad ^ (row & 7);
      half8 kf0 = *(half8*)&Ks[bf][row * 64 + g1 * 8];
      half8 kf1 = *(half8*)&Ks[bf][row * 64 + (g1 ^ 4) * 8];
      int tp = t >> 1, hi = (t & 1) * 4;
#pragma unroll
      for (int s = 0; s < 2; ++s) {
        floatx4 sacc = (floatx4){0.f, 0.f, 0.f, 0.f};
        sacc = __builtin_amdgcn_mfma_f32_16x16x32_f16(kf0, qf[s][0], sacc, 0, 0, 0);
        sacc = __builtin_amdgcn_mfma_f32_16x16x32_f16(kf1, qf[s][1], sacc, 0, 0, 0);
        float p0 = __builtin_amdgcn_exp2f(fmaf(sacc[0], cS, -FOFF));
        float p1 = __builtin_amdgcn_exp2f(fmaf(sacc[1], cS, -FOFF));
        float p2 = __builtin_amdgcn_exp2f(fmaf(sacc[2], cS, -FOFF));
        float p3 = __builtin_amdgcn_exp2f(fmaf(sacc[3], cS, -FOFF));
        lsum[s] += (p0 + p1) + (p2 + p3);
        half2v h01 = pack2(p0, p1);
        half2v h23 = pack2(p2, p3);
        half2v l01 = pack2(p0 - (float)h01[0], p1 - (float)h01[1]);
        half2v l23 = pack2(p2 - (float)h23[0], p3 - (float)h23[1]);
        aph[s][tp][hi + 0] = h01[0]; aph[s][tp][hi + 1] = h01[1];
        aph[s][tp][hi + 2] = h23[0]; aph[s][tp][hi + 3] = h23[1];
        apl[s][tp][hi + 0] = l01[0]; apl[s][tp][hi + 1] = l01[1];
        apl[s][tp][hi + 2] = l23[0]; apl[s][tp][hi + 3] = l23[1];
      }
    }

    // PV: per d-block, B-frags are 2 contiguous b128 (tp=0,1); K=32 MFMAs
#pragma unroll
    for (int d = 0; d < 4; ++d) {
      const f16* vsrow = &Vs[bf][d * 16 + l15][0];
      half8 b0 = *(const half8*)(vsrow + quad * 8);        // tp=0
      half8 b1 = *(const half8*)(vsrow + 32 + quad * 8);   // tp=1
#pragma unroll
      for (int s = 0; s < 2; ++s) {
        oacc[s][d] = __builtin_amdgcn_mfma_f32_16x16x32_f16(aph[s][0], b0, oacc[s][d], 0, 0, 0);
        oacc[s][d] = __builtin_amdgcn_mfma_f32_16x16x32_f16(apl[s][0], b0, oacc[s][d], 0, 0, 0);
        oacc[s][d] = __builtin_amdgcn_mfma_f32_16x16x32_f16(aph[s][1], b1, oacc[s][d], 0, 0, 0);
        oacc[s][d] = __builtin_amdgcn_mfma_f32_16x16x32_f16(apl[s][1], b1, oacc[s][d], 0, 0, 0);
      }
    }
  };

  // Prologue: tile 0 into buf 0; issue tile-1 V loads early.
  stageK(0, 0);
  loadV(0);
  writeV(0);
  loadV(64);
  __syncthreads();

  int buf = 0;
  for (int it = 0; it < 31; ++it) {
    stageK(buf ^ 1, (it + 1) * 64);   // K(t+1) -> other buffer
    writeV(buf ^ 1);                  // V(t+1) from regs (loaded last iter)
    if (it < 30) loadV((it + 2) * 64);
    compute(buf);                     // hides the loads above
    __syncthreads();                  // drains K(t+1)/V(t+2) loads (free)
    buf ^= 1;
  }
  compute(buf);                       // tile 31 (staged at it=30)

  // l: reduce across the 4 quads, broadcast via LDS (quad<->l15 remap)
#pragma unroll
  for (int s = 0; s < 2; ++s) {
    float l = lsum[s];
    l += __shfl_xor(l, 16);
    l += __shfl_xor(l, 32);
    lred[w][s][l15] = l;
  }
  float linv[2][4];
#pragma unroll
  for (int s = 0; s < 2; ++s)
#pragma unroll
    for (int r = 0; r < 4; ++r) linv[s][r] = sv / lred[w][s][quad * 4 + r];

  float lmax = 0.f;
#pragma unroll
  for (int s = 0; s < 2; ++s)
#pragma unroll
    for (int d = 0; d < 4; ++d)
#pragma unroll
      for (int r = 0; r < 4; ++r) {
        float hv = oacc[s][d][r] * linv[s][r];
        heads[((size_t)(q0 + w * 32 + s * 16 + quad * 4 + r) * 2 + b) * 1024 +
              h * 64 + d * 16 + l15] = hv;
        lmax = fmaxf(lmax, fabsf(hv));
      }
  red[tid] = lmax; __syncthreads();
  for (int sh = 128; sh > 0; sh >>= 1) {
    if (tid < sh) red[tid] = fmaxf(red[tid], red[tid + sh]);
    __syncthreads();
  }
  if (tid == 0) atomicMax(&slots[SLOT_HD], __float_as_uint(red[0]));
}

extern "C" void kernel_launch(void* const* d_in, const int* in_sizes, int n_in,
                              void* d_out, int out_size, void* d_ws, size_t ws_size,
                              hipStream_t stream) {
  (void)in_sizes; (void)n_in; (void)out_size; (void)ws_size;
  const float* query = (const float*)d_in[0];
  const float* key   = (const float*)d_in[1];
  const float* value = (const float*)d_in[2];
  const float* Wi    = (const float*)d_in[3];
  const float* bi    = (const float*)d_in[4];
  const float* Wo    = (const float*)d_in[5];
  const float* bo    = (const float*)d_in[6];
  float* out = (float*)d_out;

  char* p = (char*)d_ws;
  unsigned* slots = (unsigned*)p;            p += 1024;
  char* Wi8 = p;                             p += 3072 * 1024;          // 3 MB
  char* Wo8 = p;                             p += 1024 * 1024;          // 1 MB
  char* A1  = p;                             p += 12288 * 1024;         // 12 MB (q,k,v digit1)
  char* A2  = p;                             p += 12288 * 1024;         // 12 MB (q,k,v digit2)
  float* Hd = (float*)A1;                    // alias: 16 MB spans A1 + first 4MB of A2
  f16* Kint = (f16*)(A2 + 4194304);          // alias: last 8MB of A2 (after GEMM, no Hd overlap)
  float* Xq = (float*)p;                     p += 4096 * 1024 * 4;      // Xq,Xk,Xv contiguous!
  float* Y  = Xq;                            // alias: Xq dead after Qc made
  float* Xk = (float*)p;                     p += 4096 * 1024 * 4;
  f16* Qc   = (f16*)Xk;                      // alias: Xk dead after Kint made (sequential)
  float* Xv = (float*)p;                     p += 4096 * 1024 * 4;
  char* Hint8 = (char*)Xv + 4096 * 1024 * 2; // alias: Xv dead after quantv_t
  f16* Vt   = (f16*)p;                       p += 4096 * 1024 * 2;

  hipMemsetAsync(slots, 0, 64, stream);
  absmax3_k<<<2560, 256, 0, stream>>>(Wi, Wo, query, key, value, slots);
  quantw_k<<<1024, 256, 0, stream>>>(Wi, Wo, Wi8, Wo8, slots);
  digitize_k<<<3072, 256, 0, stream>>>(query, key, value, A1, A2, slots);

  dim3 gq(24, 96);  // N=3072, M=12288 (q,k,v stacked)
  gemm_qkv_i8_k<<<gq, 512, 0, stream>>>(A1, A2, Wi8, bi, Xq, slots);

  quanti2_k<<<2048, 256, 0, stream>>>(Xk, Kint, Xq, Qc, slots);

  dim3 gvt(32, 32);
  quantv_t_k<<<gvt, 256, 0, stream>>>(Xv, Vt, slots);

  dim3 ga(16, 32);
  attn_k<<<ga, 256, 0, stream>>>(Qc, Kint, Vt, Hd, slots);

  quant8_k<<<1024, 256, 0, stream>>>(Hd, Hint8, slots, SLOT_HD);

  dim3 g2(8, 32);  // N=1024, M=4096
  gemm_i8out_k<<<g2, 512, 0, stream>>>(Hint8, Wo8, bo, Y, slots);

  quantf_k<<<1024, 256, 0, stream>>>(Y, out, 1048576, slots, SLOT_Y, 1.0f);
}